// Round 14
// baseline (1192.347 us; speedup 1.0000x reference)
//
#include <hip/hip_runtime.h>
#include <math.h>

#define N_NODES 50000
#define N_EDGES 100000
#define H 768
#define NH 12
#define HD 64
#define NG 64
#define NC 10
#define H2 384
#define PCH 32   // pooling chunks per graph
#define NSB 196  // scan blocks = cdiv(N_NODES,256)
#define STRIPS 782   // cdiv(N_NODES, 64)

typedef _Float16 h8  __attribute__((ext_vector_type(8)));   // 8 fp16 (4 VGPR)
typedef _Float16 h4v __attribute__((ext_vector_type(4)));
typedef float    ffrag __attribute__((ext_vector_type(4))); // MFMA acc

// ---------------- static device scratch ----------------
__device__ float    g_bufB[(size_t)N_NODES * H];   // GAT2 fp32 out (pool input)
__device__ _Float16 g_ah[(size_t)N_NODES * H];     // GEMM input acts fp16
__device__ _Float16 g_ch[(size_t)N_NODES * H];     // GEMM output / gather input fp16
__device__ _Float16 g_wh[4 * H * H];               // 4 weights^T fp16 [N][K]
__device__ float    g_dinv[N_NODES];
__device__ int      g_degi[N_NODES];
__device__ int      g_bsum[256];
__device__ int      g_boff[256];
__device__ int      g_cursor[N_NODES];
__device__ int      g_rowptr[N_NODES + 1];
__device__ int      g_csrsrc[N_EDGES];
__device__ float    g_aS[(size_t)N_NODES * NH];
__device__ float    g_aD[(size_t)N_NODES * NH];
__device__ float    g_ppool[(size_t)NG * PCH * H]; // pooling partials (6.3 MB)
__device__ float    g_zb[NG * H2];

__device__ inline int clampi(int v, int hi) { return (v < 0) ? 0 : (v >= hi ? hi - 1 : v); }

// async global->LDS, 16B per lane: lane i writes lds_base + i*16 (wave-uniform base)
__device__ inline void gload_lds16(const _Float16* g, _Float16* s) {
    __builtin_amdgcn_global_load_lds(
        (const __attribute__((address_space(1))) void*)g,
        (__attribute__((address_space(3))) void*)s, 16, 0, 0);
}

// ---------------- CSR build ----------------
__global__ void fill_i32(int* p, int n, int v) {
    int i = blockIdx.x * blockDim.x + threadIdx.x;
    if (i < n) p[i] = v;
}

__global__ void count_deg(const int* __restrict__ dst, int* __restrict__ degi) {
    int e = blockIdx.x * blockDim.x + threadIdx.x;
    if (e < N_EDGES) atomicAdd(&degi[clampi(dst[e], N_NODES)], 1);
}

// hierarchical scan (r13-verified)
__global__ __launch_bounds__(256) void scan1(const int* __restrict__ degi, int* __restrict__ bsum) {
    __shared__ int s[256];
    int b = blockIdx.x, t = threadIdx.x;
    int idx = b * 256 + t;
    s[t] = (idx < N_NODES) ? degi[idx] : 0;
    __syncthreads();
    for (int off = 128; off > 0; off >>= 1) {
        if (t < off) s[t] += s[t + off];
        __syncthreads();
    }
    if (t == 0) bsum[b] = s[0];
}

__global__ __launch_bounds__(256) void scan2(const int* __restrict__ bsum, int* __restrict__ boff,
                                             int* __restrict__ rowptr) {
    __shared__ int s[256];
    int t = threadIdx.x;
    int v = (t < NSB) ? bsum[t] : 0;
    s[t] = v;
    __syncthreads();
    for (int off = 1; off < 256; off <<= 1) {
        int x = (t >= off) ? s[t - off] : 0;
        __syncthreads();
        s[t] += x;
        __syncthreads();
    }
    if (t < NSB) boff[t] = s[t] - v;
    if (t == NSB - 1) rowptr[N_NODES] = s[t];
}

__global__ __launch_bounds__(256) void scan3(const int* __restrict__ degi, const int* __restrict__ boff,
                                             int* __restrict__ rowptr, int* __restrict__ cursor,
                                             float* __restrict__ dinv) {
    __shared__ int s[256];
    int b = blockIdx.x, t = threadIdx.x;
    int idx = b * 256 + t;
    int v = (idx < N_NODES) ? degi[idx] : 0;
    s[t] = v;
    __syncthreads();
    for (int off = 1; off < 256; off <<= 1) {
        int x = (t >= off) ? s[t - off] : 0;
        __syncthreads();
        s[t] += x;
        __syncthreads();
    }
    if (idx < N_NODES) {
        int excl = s[t] - v + boff[b];
        rowptr[idx] = excl;
        cursor[idx] = excl;
        dinv[idx] = rsqrtf((float)v + 1.0f);   // +1 = self-loop
    }
}

__global__ void bin_edges(const int* __restrict__ src, const int* __restrict__ dst,
                          int* __restrict__ cursor, int* __restrict__ csrsrc) {
    int e = blockIdx.x * blockDim.x + threadIdx.x;
    if (e >= N_EDGES) return;
    int d = clampi(dst[e], N_NODES);
    int pos = atomicAdd(&cursor[d], 1);
    if (pos >= 0 && pos < N_EDGES) csrsrc[pos] = clampi(src[e], N_NODES);
}

// ---------------- GEMM: x@w1 (K=3), fp16 out ----------------
__global__ void gemm_k3(const float* __restrict__ x, const float* __restrict__ w,
                        _Float16* __restrict__ out) {
    int idx = blockIdx.x * blockDim.x + threadIdx.x;
    if (idx >= N_NODES * H) return;
    int n = idx / H, j = idx % H;
    float x0 = x[n*3], x1 = x[n*3+1], x2 = x[n*3+2];
    out[idx] = (_Float16)(x0 * w[j] + x1 * w[H + j] + x2 * w[2*H + j]);
}

// all 4 big weights: w[K][N] fp32 -> transposed fp16 [N][K], one launch
__global__ void split_wT4(const float* __restrict__ w2, const float* __restrict__ w3,
                          const float* __restrict__ wg1, const float* __restrict__ wg2,
                          _Float16* __restrict__ out) {
    int idx = blockIdx.x * blockDim.x + threadIdx.x;
    if (idx >= 4 * H * H) return;
    int l = idx / (H * H), r = idx % (H * H);
    const float* w = (l == 0) ? w2 : (l == 1) ? w3 : (l == 2) ? wg1 : wg2;
    int n = r % H, k = r / H;
    out[(size_t)l * H * H + (size_t)n * H + k] = (_Float16)w[(size_t)k * H + n];
}

// ---------------- fp16 MFMA GEMM, double-buffered, fp16 C, 64x128 tile -------
// r13 evidence: 128x128 tile ran at 2.3 blocks/CU (Occ 28%) -> barrier-latency
// bound (MfmaUtil 18%, hbm 13%). 64x128 halves acc VGPRs (32) and LDS (24 KB
// dbuf) -> ~2x resident blocks for latency hiding. Wave tile 32x64 = one full
// head per wave, so the r8-verified fused-alpha epilogue still works.
// Staging: 12 segs of 16 rows x 32k (4 A + 8 B), 3 per wave, global_load_lds
// width=16, double-buffered (r10-proven loop). XCD swizzle r6-verified.
__global__ __launch_bounds__(256) void gemm_f16(const _Float16* __restrict__ a,
                                                const _Float16* __restrict__ bt,
                                                _Float16* __restrict__ C, int M,
                                                const float* __restrict__ asf,
                                                const float* __restrict__ adf,
                                                float* __restrict__ aS,
                                                float* __restrict__ aD) {
    __shared__ _Float16 sA[2][64 * 32], sB[2][128 * 32];
    int tid = threadIdx.x;
    int wave = tid >> 6, lane = tid & 63;
    int quad = lane >> 4, l16 = lane & 15;

    int id = blockIdx.x;
    int x = id & 7;
    int s = id >> 3;
    int strip = x + 8 * (s / 6);
    int colt = s % 6;
    if (strip >= STRIPS) return;
    int row0 = strip * 64, col0 = colt * 128;
    int wr = (wave >> 1) * 32, wc = (wave & 1) * 64;

    // staging: 12 segs (0-3 = A rows, 4-11 = B rows), wave w stages 3w..3w+2
    int rr = lane >> 2, kc = (lane & 3) << 3;   // 4 lanes/row, 8-half chunks
    const _Float16* gptr[3];
    _Float16* sd0[3];
    _Float16* sd1[3];
    #pragma unroll
    for (int k = 0; k < 3; k++) {
        int sg = wave * 3 + k;
        int isA = (sg < 4);
        int srow = isA ? sg : sg - 4;
        int r = (isA ? row0 : col0) + srow * 16 + rr;
        if (isA && r >= M) r = M - 1;   // clamped rows feed unstored C rows
        gptr[k] = (isA ? a : bt) + (size_t)r * H + kc;
        sd0[k] = (isA ? sA[0] : sB[0]) + srow * 512;
        sd1[k] = (isA ? sA[1] : sB[1]) + srow * 512;
    }

    ffrag acc[2][4];
    #pragma unroll
    for (int i = 0; i < 2; i++)
        #pragma unroll
        for (int j = 0; j < 4; j++) { ffrag z = {0.f, 0.f, 0.f, 0.f}; acc[i][j] = z; }

    // prologue: stage k-tile 0 into buf 0
    #pragma unroll
    for (int k = 0; k < 3; k++)
        gload_lds16(gptr[k], sd0[k]);

    #pragma unroll 1
    for (int kt = 0; kt < H / 32; kt++) {
        int cur = kt & 1;
        __syncthreads();   // buf[cur] loads complete (compiler vmcnt drain)
        if (kt + 1 < H / 32) {
            int koff = (kt + 1) * 32;
            #pragma unroll
            for (int k = 0; k < 3; k++)
                gload_lds16(gptr[k] + koff, (cur ? sd0[k] : sd1[k]));
        }

        const _Float16* pA = sA[cur];
        const _Float16* pB = sB[cur];
        h8 fa[2], fb[4];
        #pragma unroll
        for (int i = 0; i < 2; i++)
            fa[i] = *reinterpret_cast<const h8*>(&pA[(wr + i * 16 + l16) * 32 + quad * 8]);
        #pragma unroll
        for (int j = 0; j < 4; j++)
            fb[j] = *reinterpret_cast<const h8*>(&pB[(wc + j * 16 + l16) * 32 + quad * 8]);
        #pragma unroll
        for (int i = 0; i < 2; i++)
            #pragma unroll
            for (int j = 0; j < 4; j++)
                acc[i][j] = __builtin_amdgcn_mfma_f32_16x16x32_f16(fa[i], fb[j], acc[i][j], 0, 0, 0);
    }

    // epilogue: C/D layout col=lane&15, row=quad*4+reg (m89-verified); fp16 store
    #pragma unroll
    for (int i = 0; i < 2; i++)
        #pragma unroll
        for (int r = 0; r < 4; r++) {
            int row = row0 + wr + i * 16 + quad * 4 + r;
            if (row >= M) continue;
            #pragma unroll
            for (int j = 0; j < 4; j++)
                C[(size_t)row * H + col0 + wc + j * 16 + l16] = (_Float16)acc[i][j][r];
        }

    // fused GAT alpha: this wave covers one full head (64 cols) for 32 rows
    if (asf) {
        int head = (col0 + wc) >> 6;
        float as_c[4], ad_c[4];
        #pragma unroll
        for (int j = 0; j < 4; j++) {
            int col = col0 + wc + j * 16 + l16;
            as_c[j] = asf[col];
            ad_c[j] = adf[col];
        }
        #pragma unroll
        for (int i = 0; i < 2; i++)
            #pragma unroll
            for (int r = 0; r < 4; r++) {
                float ps = 0.f, pd = 0.f;
                #pragma unroll
                for (int j = 0; j < 4; j++) {
                    ps += acc[i][j][r] * as_c[j];
                    pd += acc[i][j][r] * ad_c[j];
                }
                ps += __shfl_xor(ps, 1);  pd += __shfl_xor(pd, 1);
                ps += __shfl_xor(ps, 2);  pd += __shfl_xor(pd, 2);
                ps += __shfl_xor(ps, 4);  pd += __shfl_xor(pd, 4);
                ps += __shfl_xor(ps, 8);  pd += __shfl_xor(pd, 8);
                int row = row0 + wr + i * 16 + quad * 4 + r;
                if (l16 == 0 && row < M) {
                    aS[row * NH + head] = ps;
                    aD[row * NH + head] = pd;
                }
            }
    }
}

// ------- fused GCN gather: 2 nodes/block, 16B h8 loads, fp32 accum, fp16 out --
__global__ void gcn_gather(const int* __restrict__ rowptr, const int* __restrict__ csrsrc,
                           const _Float16* __restrict__ h, const float* __restrict__ dinv,
                           const float* __restrict__ bias, _Float16* __restrict__ hi) {
    int d = blockIdx.x * 2 + (threadIdx.x / 96);
    int t = threadIdx.x % 96;   // h8-chunk index (96 x 8 halves = 768)
    if (d >= N_NODES) return;
    float dd = dinv[d];
    float c = dd * dd;
    h8 v = ((const h8*)(h + (size_t)d * H))[t];
    float acc[8];
    #pragma unroll
    for (int k = 0; k < 8; k++) acc[k] = (float)v[k] * c;
    int beg = rowptr[d], end = rowptr[d + 1];
    for (int i = beg; i < end; i++) {
        int s = csrsrc[i];
        float cc = dinv[s] * dd;
        h8 u = ((const h8*)(h + (size_t)s * H))[t];
        #pragma unroll
        for (int k = 0; k < 8; k++) acc[k] += (float)u[k] * cc;
    }
    float4 b0 = ((const float4*)bias)[2 * t];
    float4 b1 = ((const float4*)bias)[2 * t + 1];
    h8 o;
    o[0] = (_Float16)fmaxf(acc[0] + b0.x, 0.f);
    o[1] = (_Float16)fmaxf(acc[1] + b0.y, 0.f);
    o[2] = (_Float16)fmaxf(acc[2] + b0.z, 0.f);
    o[3] = (_Float16)fmaxf(acc[3] + b0.w, 0.f);
    o[4] = (_Float16)fmaxf(acc[4] + b1.x, 0.f);
    o[5] = (_Float16)fmaxf(acc[5] + b1.y, 0.f);
    o[6] = (_Float16)fmaxf(acc[6] + b1.z, 0.f);
    o[7] = (_Float16)fmaxf(acc[7] + b1.w, 0.f);
    ((h8*)(hi + (size_t)d * H))[t] = o;
}

__device__ inline float lrelu(float v) { return (v > 0.f) ? v : 0.2f * v; }

// fused softmax + aggregation + bias (+relu); 2 nodes/block, 16B h8 loads.
// chunk t covers cols [8t,8t+8) -> head = t>>3.
__global__ void gat_gather(const int* __restrict__ rowptr, const int* __restrict__ csrsrc,
                           const _Float16* __restrict__ h, const float* __restrict__ aS,
                           const float* __restrict__ aD, const float* __restrict__ bias,
                           float* __restrict__ out, _Float16* __restrict__ hi, int relu) {
    int d = blockIdx.x * 2 + (threadIdx.x / 96);
    int t = threadIdx.x % 96;
    if (d >= N_NODES) return;
    int hh = t >> 3;
    int beg = rowptr[d], end = rowptr[d + 1];
    float adv = aD[d * NH + hh];
    float eself = lrelu(aS[d * NH + hh] + adv);
    float m = eself;
    for (int i = beg; i < end; i++)
        m = fmaxf(m, lrelu(aS[csrsrc[i] * NH + hh] + adv));
    float ssum = __expf(eself - m);
    for (int i = beg; i < end; i++)
        ssum += __expf(lrelu(aS[csrsrc[i] * NH + hh] + adv) - m);
    float inv = 1.0f / ssum;
    float cself = __expf(eself - m) * inv;
    h8 v = ((const h8*)(h + (size_t)d * H))[t];
    float acc[8];
    #pragma unroll
    for (int k = 0; k < 8; k++) acc[k] = (float)v[k] * cself;
    for (int i = beg; i < end; i++) {
        int s = csrsrc[i];
        float c = __expf(lrelu(aS[s * NH + hh] + adv) - m) * inv;
        h8 u = ((const h8*)(h + (size_t)s * H))[t];
        #pragma unroll
        for (int k = 0; k < 8; k++) acc[k] += (float)u[k] * c;
    }
    float4 b0 = ((const float4*)bias)[2 * t];
    float4 b1 = ((const float4*)bias)[2 * t + 1];
    acc[0] += b0.x; acc[1] += b0.y; acc[2] += b0.z; acc[3] += b0.w;
    acc[4] += b1.x; acc[5] += b1.y; acc[6] += b1.z; acc[7] += b1.w;
    if (relu) {
        #pragma unroll
        for (int k = 0; k < 8; k++) acc[k] = fmaxf(acc[k], 0.f);
    }
    if (hi) {
        h8 o;
        #pragma unroll
        for (int k = 0; k < 8; k++) o[k] = (_Float16)acc[k];
        ((h8*)(hi + (size_t)d * H))[t] = o;
    } else {
        float4 o0; o0.x = acc[0]; o0.y = acc[1]; o0.z = acc[2]; o0.w = acc[3];
        float4 o1; o1.x = acc[4]; o1.y = acc[5]; o1.z = acc[6]; o1.w = acc[7];
        ((float4*)(out + (size_t)d * H))[2 * t] = o0;
        ((float4*)(out + (size_t)d * H))[2 * t + 1] = o1;
    }
}

// ---------------- pooling (batch is sorted), two-stage + fused mlp1 ----------------
__device__ inline int lower_bound_i(const int* b, int n, int key) {
    int lo = 0, hi = n;
    while (lo < hi) { int mid = (lo + hi) >> 1; if (b[mid] < key) lo = mid + 1; else hi = mid; }
    return lo;
}

__global__ void pool_partial(const int* __restrict__ batch, const float* __restrict__ h,
                             float* __restrict__ ppool) {
    int g = blockIdx.x / PCH, c = blockIdx.x % PCH;
    int t = threadIdx.x;   // 0..191
    int lo = lower_bound_i(batch, N_NODES, g);
    int hi = lower_bound_i(batch, N_NODES, g + 1);
    int len = hi - lo;
    int chunk = (len + PCH - 1) / PCH;
    int s = lo + c * chunk;
    int e = s + chunk; if (e > hi) e = hi;
    float4 a = {0, 0, 0, 0};
    for (int n = s; n < e; n++) {
        float4 v = ((const float4*)(h + (size_t)n * H))[t];
        a.x += v.x; a.y += v.y; a.z += v.z; a.w += v.w;
    }
    ((float4*)(ppool + (size_t)blockIdx.x * H))[t] = a;
}

__global__ __launch_bounds__(384) void pool_mlp1(const int* __restrict__ batch,
                                                 const float* __restrict__ ppool,
                                                 const float* __restrict__ wc1,
                                                 const float* __restrict__ bc1,
                                                 float* __restrict__ z) {
    __shared__ float row[H];
    int g = blockIdx.x, t = threadIdx.x;   // 384 threads
    int lo = lower_bound_i(batch, N_NODES, g);
    int hi = lower_bound_i(batch, N_NODES, g + 1);
    float inv = 1.0f / fmaxf((float)(hi - lo), 1.0f);
    for (int c0 = t; c0 < H; c0 += 384) {
        float a = 0.f;
        for (int c = 0; c < PCH; c++) a += ppool[(size_t)(g * PCH + c) * H + c0];
        row[c0] = a * inv;
    }
    __syncthreads();
    float acc = bc1[t];
    for (int k = 0; k < H; k++) acc += row[k] * wc1[(size_t)k * H2 + t];
    z[g * H2 + t] = fmaxf(acc, 0.f);
}

__global__ void mlp2(const float* __restrict__ z, const float* __restrict__ w,
                     const float* __restrict__ b, float* __restrict__ out) {
    int idx = blockIdx.x * blockDim.x + threadIdx.x;
    if (idx >= NG * NC) return;
    int gg = idx / NC, c = idx % NC;
    const float* zp = z + (size_t)gg * H2;
    float acc = b[c];
    for (int k = 0; k < H2; k++) acc += zp[k] * w[(size_t)k * NC + c];
    out[idx] = acc;
}

// ---------------- launch ----------------
extern "C" void kernel_launch(void* const* d_in, const int* in_sizes, int n_in,
                              void* d_out, int out_size, void* d_ws, size_t ws_size,
                              hipStream_t stream) {
    (void)d_ws; (void)ws_size;
    const float* x     = (const float*)d_in[0];
    const int*   ei    = (const int*)d_in[1];
    const int*   batch = (const int*)d_in[2];
    const float* w1  = (const float*)d_in[3];  const float* b1  = (const float*)d_in[4];
    const float* w2  = (const float*)d_in[5];  const float* b2  = (const float*)d_in[6];
    const float* w3  = (const float*)d_in[7];  const float* b3  = (const float*)d_in[8];
    const float* wg1 = (const float*)d_in[9];  const float* as1 = (const float*)d_in[10];
    const float* ad1 = (const float*)d_in[11]; const float* bg1 = (const float*)d_in[12];
    const float* wg2 = (const float*)d_in[13]; const float* as2 = (const float*)d_in[14];
    const float* ad2 = (const float*)d_in[15]; const float* bg2 = (const float*)d_in[16];
    const float* wc1 = (const float*)d_in[17]; const float* bc1 = (const float*)d_in[18];
    const float* wc2 = (const float*)d_in[19]; const float* bc2 = (const float*)d_in[20];

    const int* srcp = ei;            // edge_index[0]
    const int* dstp = ei + N_EDGES;  // edge_index[1]

    float *bufB, *dinv, *aS, *aD, *ppool, *zb;
    _Float16 *ah, *ch, *wh;
    int *degi, *bsum, *boff, *cursor, *rowptr, *csrsrc;
    hipGetSymbolAddress((void**)&bufB,   HIP_SYMBOL(g_bufB));
    hipGetSymbolAddress((void**)&ah,     HIP_SYMBOL(g_ah));
    hipGetSymbolAddress((void**)&ch,     HIP_SYMBOL(g_ch));
    hipGetSymbolAddress((void**)&wh,     HIP_SYMBOL(g_wh));
    hipGetSymbolAddress((void**)&dinv,   HIP_SYMBOL(g_dinv));
    hipGetSymbolAddress((void**)&degi,   HIP_SYMBOL(g_degi));
    hipGetSymbolAddress((void**)&bsum,   HIP_SYMBOL(g_bsum));
    hipGetSymbolAddress((void**)&boff,   HIP_SYMBOL(g_boff));
    hipGetSymbolAddress((void**)&cursor, HIP_SYMBOL(g_cursor));
    hipGetSymbolAddress((void**)&rowptr, HIP_SYMBOL(g_rowptr));
    hipGetSymbolAddress((void**)&csrsrc, HIP_SYMBOL(g_csrsrc));
    hipGetSymbolAddress((void**)&aS,     HIP_SYMBOL(g_aS));
    hipGetSymbolAddress((void**)&aD,     HIP_SYMBOL(g_aD));
    hipGetSymbolAddress((void**)&ppool,  HIP_SYMBOL(g_ppool));
    hipGetSymbolAddress((void**)&zb,     HIP_SYMBOL(g_zb));

    auto cdiv = [](int a, int b) { return (a + b - 1) / b; };
    int ggrid = 8 * cdiv(STRIPS, 8) * (H / 128);   // 784 * 6 = 4704
    int ngath = cdiv(N_NODES, 2);                  // 25000, 2 nodes/block
    size_t HH = (size_t)H * H;

    // ---- weight transpose+cast, one launch, off the critical path ----
    split_wT4<<<cdiv(4*H*H,256),256,0,stream>>>(w2, w3, wg1, wg2, wh);

    // ---- CSR build (hierarchical scan) ----
    fill_i32<<<cdiv(N_NODES,256),256,0,stream>>>(degi, N_NODES, 0);
    count_deg<<<cdiv(N_EDGES,256),256,0,stream>>>(dstp, degi);
    scan1<<<NSB,256,0,stream>>>(degi, bsum);
    scan2<<<1,256,0,stream>>>(bsum, boff, rowptr);
    scan3<<<NSB,256,0,stream>>>(degi, boff, rowptr, cursor, dinv);
    bin_edges<<<cdiv(N_EDGES,256),256,0,stream>>>(srcp, dstp, cursor, csrsrc);

    // ---- GCN1 (K=3 GEMM stays fp32 vector math, fp16 out) ----
    gemm_k3<<<cdiv(N_NODES*H,256),256,0,stream>>>(x, w1, ch);
    gcn_gather<<<ngath,192,0,stream>>>(rowptr, csrsrc, ch, dinv, b1, ah);

    // ---- GCN2 ----
    gemm_f16<<<ggrid,256,0,stream>>>(ah, wh + 0*HH, ch, N_NODES,
                                     (const float*)nullptr, (const float*)nullptr,
                                     (float*)nullptr, (float*)nullptr);
    gcn_gather<<<ngath,192,0,stream>>>(rowptr, csrsrc, ch, dinv, b2, ah);

    // ---- GCN3 ----
    gemm_f16<<<ggrid,256,0,stream>>>(ah, wh + 1*HH, ch, N_NODES,
                                     (const float*)nullptr, (const float*)nullptr,
                                     (float*)nullptr, (float*)nullptr);
    gcn_gather<<<ngath,192,0,stream>>>(rowptr, csrsrc, ch, dinv, b3, ah);

    // ---- GAT1 (alpha fused into GEMM epilogue) ----
    gemm_f16<<<ggrid,256,0,stream>>>(ah, wh + 2*HH, ch, N_NODES, as1, ad1, aS, aD);
    gat_gather<<<ngath,192,0,stream>>>(rowptr, csrsrc, ch, aS, aD, bg1,
                                       (float*)nullptr, ah, 1);

    // ---- GAT2 (no relu; fp32 out for pooling) ----
    gemm_f16<<<ggrid,256,0,stream>>>(ah, wh + 3*HH, ch, N_NODES, as2, ad2, aS, aD);
    gat_gather<<<ngath,192,0,stream>>>(rowptr, csrsrc, ch, aS, aD, bg2,
                                       bufB, (_Float16*)nullptr, 0);

    // ---- pool (two-stage; stage-2 fused with mlp1) + classifier ----
    pool_partial<<<NG*PCH,192,0,stream>>>(batch, bufB, ppool);
    pool_mlp1<<<NG,384,0,stream>>>(batch, ppool, wc1, bc1, zb);
    mlp2<<<cdiv(NG*NC,64),64,0,stream>>>(zb, wc2, bc2, (float*)d_out);
}

// Round 15
// 1062.457 us; speedup vs baseline: 1.1223x; 1.1223x over previous
//
#include <hip/hip_runtime.h>
#include <math.h>

#define N_NODES 50000
#define N_EDGES 100000
#define H 768
#define NH 12
#define HD 64
#define NG 64
#define NC 10
#define H2 384
#define PCH 32   // pooling chunks per graph
#define NSB 196  // scan blocks = cdiv(N_NODES,256)

typedef _Float16 h8  __attribute__((ext_vector_type(8)));   // 8 fp16 (4 VGPR)
typedef _Float16 h4v __attribute__((ext_vector_type(4)));
typedef float    ffrag __attribute__((ext_vector_type(4))); // MFMA acc

// ---------------- static device scratch ----------------
__device__ float    g_bufB[(size_t)N_NODES * H];   // GAT2 fp32 out (pool input)
__device__ _Float16 g_ah[(size_t)N_NODES * H];     // GEMM input acts fp16
__device__ _Float16 g_ch[(size_t)N_NODES * H];     // GEMM output / gather input fp16
__device__ _Float16 g_wh[4 * H * H];               // 4 weights^T fp16 [N][K]
__device__ float    g_dinv[N_NODES];
__device__ int      g_degi[N_NODES];
__device__ int      g_bsum[256];
__device__ int      g_boff[256];
__device__ int      g_cursor[N_NODES];
__device__ int      g_rowptr[N_NODES + 1];
__device__ int      g_csrsrc[N_EDGES];
__device__ float    g_aS[(size_t)N_NODES * NH];
__device__ float    g_aD[(size_t)N_NODES * NH];
__device__ float    g_ppool[(size_t)NG * PCH * H]; // pooling partials (6.3 MB)
__device__ float    g_zb[NG * H2];

__device__ inline int clampi(int v, int hi) { return (v < 0) ? 0 : (v >= hi ? hi - 1 : v); }

// async global->LDS, 16B per lane: lane i writes lds_base + i*16 (wave-uniform base)
__device__ inline void gload_lds16(const _Float16* g, _Float16* s) {
    __builtin_amdgcn_global_load_lds(
        (const __attribute__((address_space(1))) void*)g,
        (__attribute__((address_space(3))) void*)s, 16, 0, 0);
}

// ---------------- CSR build ----------------
__global__ void fill_i32(int* p, int n, int v) {
    int i = blockIdx.x * blockDim.x + threadIdx.x;
    if (i < n) p[i] = v;
}

__global__ void count_deg(const int* __restrict__ dst, int* __restrict__ degi) {
    int e = blockIdx.x * blockDim.x + threadIdx.x;
    if (e < N_EDGES) atomicAdd(&degi[clampi(dst[e], N_NODES)], 1);
}

// hierarchical scan (r13-verified)
__global__ __launch_bounds__(256) void scan1(const int* __restrict__ degi, int* __restrict__ bsum) {
    __shared__ int s[256];
    int b = blockIdx.x, t = threadIdx.x;
    int idx = b * 256 + t;
    s[t] = (idx < N_NODES) ? degi[idx] : 0;
    __syncthreads();
    for (int off = 128; off > 0; off >>= 1) {
        if (t < off) s[t] += s[t + off];
        __syncthreads();
    }
    if (t == 0) bsum[b] = s[0];
}

__global__ __launch_bounds__(256) void scan2(const int* __restrict__ bsum, int* __restrict__ boff,
                                             int* __restrict__ rowptr) {
    __shared__ int s[256];
    int t = threadIdx.x;
    int v = (t < NSB) ? bsum[t] : 0;
    s[t] = v;
    __syncthreads();
    for (int off = 1; off < 256; off <<= 1) {
        int x = (t >= off) ? s[t - off] : 0;
        __syncthreads();
        s[t] += x;
        __syncthreads();
    }
    if (t < NSB) boff[t] = s[t] - v;
    if (t == NSB - 1) rowptr[N_NODES] = s[t];
}

__global__ __launch_bounds__(256) void scan3(const int* __restrict__ degi, const int* __restrict__ boff,
                                             int* __restrict__ rowptr, int* __restrict__ cursor,
                                             float* __restrict__ dinv) {
    __shared__ int s[256];
    int b = blockIdx.x, t = threadIdx.x;
    int idx = b * 256 + t;
    int v = (idx < N_NODES) ? degi[idx] : 0;
    s[t] = v;
    __syncthreads();
    for (int off = 1; off < 256; off <<= 1) {
        int x = (t >= off) ? s[t - off] : 0;
        __syncthreads();
        s[t] += x;
        __syncthreads();
    }
    if (idx < N_NODES) {
        int excl = s[t] - v + boff[b];
        rowptr[idx] = excl;
        cursor[idx] = excl;
        dinv[idx] = rsqrtf((float)v + 1.0f);   // +1 = self-loop
    }
}

__global__ void bin_edges(const int* __restrict__ src, const int* __restrict__ dst,
                          int* __restrict__ cursor, int* __restrict__ csrsrc) {
    int e = blockIdx.x * blockDim.x + threadIdx.x;
    if (e >= N_EDGES) return;
    int d = clampi(dst[e], N_NODES);
    int pos = atomicAdd(&cursor[d], 1);
    if (pos >= 0 && pos < N_EDGES) csrsrc[pos] = clampi(src[e], N_NODES);
}

// ---------------- GEMM: x@w1 (K=3), fp16 out ----------------
__global__ void gemm_k3(const float* __restrict__ x, const float* __restrict__ w,
                        _Float16* __restrict__ out) {
    int idx = blockIdx.x * blockDim.x + threadIdx.x;
    if (idx >= N_NODES * H) return;
    int n = idx / H, j = idx % H;
    float x0 = x[n*3], x1 = x[n*3+1], x2 = x[n*3+2];
    out[idx] = (_Float16)(x0 * w[j] + x1 * w[H + j] + x2 * w[2*H + j]);
}

// all 4 big weights: w[K][N] fp32 -> transposed fp16 [N][K], one launch
__global__ void split_wT4(const float* __restrict__ w2, const float* __restrict__ w3,
                          const float* __restrict__ wg1, const float* __restrict__ wg2,
                          _Float16* __restrict__ out) {
    int idx = blockIdx.x * blockDim.x + threadIdx.x;
    if (idx >= 4 * H * H) return;
    int l = idx / (H * H), r = idx % (H * H);
    const float* w = (l == 0) ? w2 : (l == 1) ? w3 : (l == 2) ? wg1 : wg2;
    int n = r % H, k = r / H;
    out[(size_t)l * H * H + (size_t)n * H + k] = (_Float16)w[(size_t)k * H + n];
}

// ------ fp16 MFMA GEMM, 128x128 tile, double-buffered, fp16 C, XOR-swizzled ------
// r14 post-mortem: 64x128 tile regressed (168 us, MfmaUtil 14.7%) -- staging and
// ds_read per MFMA both worsened. Reverted to r13's 128x128 dbuf (131-137 us).
// New: XOR chunk swizzle kills the 7.2e6 LDS bank conflicts. Staging lane loads
// global chunk (lane&3)^((lane>>3)&3) (global_load_lds LDS slots are lane-fixed;
// we permute the SOURCE); fragment read uses slot quad^((l16>>1)&3). Per quad the
// 16 lanes then spread over all 8 (parity x chunk) bank groups = 2-way = free.
__global__ __launch_bounds__(256) void gemm_f16(const _Float16* __restrict__ a,
                                                const _Float16* __restrict__ bt,
                                                _Float16* __restrict__ C, int M,
                                                const float* __restrict__ asf,
                                                const float* __restrict__ adf,
                                                float* __restrict__ aS,
                                                float* __restrict__ aD) {
    __shared__ _Float16 sA[2][128 * 32], sB[2][128 * 32];
    int tid = threadIdx.x;
    int wave = tid >> 6, lane = tid & 63;
    int quad = lane >> 4, l16 = lane & 15;

    int id = blockIdx.x;
    int x = id & 7;
    int s = id >> 3;
    int strip = x + 8 * (s / 6);
    int colt = s % 6;
    if (strip >= (N_NODES + 127) / 128) return;
    int row0 = strip * 128, col0 = colt * 128;
    int wr = (wave >> 1) * 64, wc = (wave & 1) * 64;

    // staging: waves 0,1 -> A segs 0-3 / 4-7; waves 2,3 -> B segs 0-3 / 4-7
    int isA = (wave < 2);
    const _Float16* gsrc = isA ? a : bt;
    int gbase = isA ? row0 : col0;
    int segbase = (wave & 1) * 4;
    int rr = lane >> 2;
    int kc = (((lane & 3) ^ ((lane >> 3) & 3)) << 3);   // XOR-swizzled source chunk
    const _Float16* gptr[4];
    int soff[4];
    #pragma unroll
    for (int k = 0; k < 4; k++) {
        int seg = segbase + k;
        int r = gbase + seg * 16 + rr;
        if (isA && r >= M) r = M - 1;   // clamped rows feed unstored C rows
        gptr[k] = gsrc + (size_t)r * H + kc;
        soff[k] = seg * 512;
    }
    _Float16* sd0 = isA ? sA[0] : sB[0];
    _Float16* sd1 = isA ? sA[1] : sB[1];

    // fragment-read swizzle: slot = quad ^ ((l16>>1)&3), constant per lane
    int fsw = (quad ^ ((l16 >> 1) & 3)) * 8;

    ffrag acc[4][4];
    #pragma unroll
    for (int i = 0; i < 4; i++)
        #pragma unroll
        for (int j = 0; j < 4; j++) { ffrag z = {0.f, 0.f, 0.f, 0.f}; acc[i][j] = z; }

    // prologue: stage k-tile 0 into buf 0
    #pragma unroll
    for (int k = 0; k < 4; k++)
        gload_lds16(gptr[k], sd0 + soff[k]);

    #pragma unroll 1
    for (int kt = 0; kt < H / 32; kt++) {
        int cur = kt & 1;
        __syncthreads();   // buf[cur] loads complete (compiler vmcnt drain)
        if (kt + 1 < H / 32) {
            _Float16* nb = cur ? sd0 : sd1;
            int koff = (kt + 1) * 32;
            #pragma unroll
            for (int k = 0; k < 4; k++)
                gload_lds16(gptr[k] + koff, nb + soff[k]);
        }

        const _Float16* pA = sA[cur];
        const _Float16* pB = sB[cur];
        h8 fa[4], fb[4];
        #pragma unroll
        for (int i = 0; i < 4; i++)
            fa[i] = *reinterpret_cast<const h8*>(&pA[(wr + i * 16 + l16) * 32 + fsw]);
        #pragma unroll
        for (int j = 0; j < 4; j++)
            fb[j] = *reinterpret_cast<const h8*>(&pB[(wc + j * 16 + l16) * 32 + fsw]);
        #pragma unroll
        for (int i = 0; i < 4; i++)
            #pragma unroll
            for (int j = 0; j < 4; j++)
                acc[i][j] = __builtin_amdgcn_mfma_f32_16x16x32_f16(fa[i], fb[j], acc[i][j], 0, 0, 0);
    }

    // epilogue: C/D layout col=lane&15, row=quad*4+reg (m89-verified); fp16 store
    #pragma unroll
    for (int i = 0; i < 4; i++)
        #pragma unroll
        for (int r = 0; r < 4; r++) {
            int row = row0 + wr + i * 16 + quad * 4 + r;
            if (row >= M) continue;
            #pragma unroll
            for (int j = 0; j < 4; j++)
                C[(size_t)row * H + col0 + wc + j * 16 + l16] = (_Float16)acc[i][j][r];
        }

    // fused GAT alpha: this wave covers one full head (64 cols) for 64 rows
    if (asf) {
        int head = (col0 + wc) >> 6;
        float as_c[4], ad_c[4];
        #pragma unroll
        for (int j = 0; j < 4; j++) {
            int col = col0 + wc + j * 16 + l16;
            as_c[j] = asf[col];
            ad_c[j] = adf[col];
        }
        #pragma unroll
        for (int i = 0; i < 4; i++)
            #pragma unroll
            for (int r = 0; r < 4; r++) {
                float ps = 0.f, pd = 0.f;
                #pragma unroll
                for (int j = 0; j < 4; j++) {
                    ps += acc[i][j][r] * as_c[j];
                    pd += acc[i][j][r] * ad_c[j];
                }
                ps += __shfl_xor(ps, 1);  pd += __shfl_xor(pd, 1);
                ps += __shfl_xor(ps, 2);  pd += __shfl_xor(pd, 2);
                ps += __shfl_xor(ps, 4);  pd += __shfl_xor(pd, 4);
                ps += __shfl_xor(ps, 8);  pd += __shfl_xor(pd, 8);
                int row = row0 + wr + i * 16 + quad * 4 + r;
                if (l16 == 0 && row < M) {
                    aS[row * NH + head] = ps;
                    aD[row * NH + head] = pd;
                }
            }
    }
}

// ------- fused GCN gather: 2 nodes/block, 16B h8 loads (r14-verified) --------
__global__ void gcn_gather(const int* __restrict__ rowptr, const int* __restrict__ csrsrc,
                           const _Float16* __restrict__ h, const float* __restrict__ dinv,
                           const float* __restrict__ bias, _Float16* __restrict__ hi) {
    int d = blockIdx.x * 2 + (threadIdx.x / 96);
    int t = threadIdx.x % 96;   // h8-chunk index (96 x 8 halves = 768)
    if (d >= N_NODES) return;
    float dd = dinv[d];
    float c = dd * dd;
    h8 v = ((const h8*)(h + (size_t)d * H))[t];
    float acc[8];
    #pragma unroll
    for (int k = 0; k < 8; k++) acc[k] = (float)v[k] * c;
    int beg = rowptr[d], end = rowptr[d + 1];
    for (int i = beg; i < end; i++) {
        int s = csrsrc[i];
        float cc = dinv[s] * dd;
        h8 u = ((const h8*)(h + (size_t)s * H))[t];
        #pragma unroll
        for (int k = 0; k < 8; k++) acc[k] += (float)u[k] * cc;
    }
    float4 b0 = ((const float4*)bias)[2 * t];
    float4 b1 = ((const float4*)bias)[2 * t + 1];
    h8 o;
    o[0] = (_Float16)fmaxf(acc[0] + b0.x, 0.f);
    o[1] = (_Float16)fmaxf(acc[1] + b0.y, 0.f);
    o[2] = (_Float16)fmaxf(acc[2] + b0.z, 0.f);
    o[3] = (_Float16)fmaxf(acc[3] + b0.w, 0.f);
    o[4] = (_Float16)fmaxf(acc[4] + b1.x, 0.f);
    o[5] = (_Float16)fmaxf(acc[5] + b1.y, 0.f);
    o[6] = (_Float16)fmaxf(acc[6] + b1.z, 0.f);
    o[7] = (_Float16)fmaxf(acc[7] + b1.w, 0.f);
    ((h8*)(hi + (size_t)d * H))[t] = o;
}

__device__ inline float lrelu(float v) { return (v > 0.f) ? v : 0.2f * v; }

// fused softmax + aggregation + bias (+relu); 2 nodes/block, 16B h8 loads.
__global__ void gat_gather(const int* __restrict__ rowptr, const int* __restrict__ csrsrc,
                           const _Float16* __restrict__ h, const float* __restrict__ aS,
                           const float* __restrict__ aD, const float* __restrict__ bias,
                           float* __restrict__ out, _Float16* __restrict__ hi, int relu) {
    int d = blockIdx.x * 2 + (threadIdx.x / 96);
    int t = threadIdx.x % 96;
    if (d >= N_NODES) return;
    int hh = t >> 3;
    int beg = rowptr[d], end = rowptr[d + 1];
    float adv = aD[d * NH + hh];
    float eself = lrelu(aS[d * NH + hh] + adv);
    float m = eself;
    for (int i = beg; i < end; i++)
        m = fmaxf(m, lrelu(aS[csrsrc[i] * NH + hh] + adv));
    float ssum = __expf(eself - m);
    for (int i = beg; i < end; i++)
        ssum += __expf(lrelu(aS[csrsrc[i] * NH + hh] + adv) - m);
    float inv = 1.0f / ssum;
    float cself = __expf(eself - m) * inv;
    h8 v = ((const h8*)(h + (size_t)d * H))[t];
    float acc[8];
    #pragma unroll
    for (int k = 0; k < 8; k++) acc[k] = (float)v[k] * cself;
    for (int i = beg; i < end; i++) {
        int s = csrsrc[i];
        float c = __expf(lrelu(aS[s * NH + hh] + adv) - m) * inv;
        h8 u = ((const h8*)(h + (size_t)s * H))[t];
        #pragma unroll
        for (int k = 0; k < 8; k++) acc[k] += (float)u[k] * c;
    }
    float4 b0 = ((const float4*)bias)[2 * t];
    float4 b1 = ((const float4*)bias)[2 * t + 1];
    acc[0] += b0.x; acc[1] += b0.y; acc[2] += b0.z; acc[3] += b0.w;
    acc[4] += b1.x; acc[5] += b1.y; acc[6] += b1.z; acc[7] += b1.w;
    if (relu) {
        #pragma unroll
        for (int k = 0; k < 8; k++) acc[k] = fmaxf(acc[k], 0.f);
    }
    if (hi) {
        h8 o;
        #pragma unroll
        for (int k = 0; k < 8; k++) o[k] = (_Float16)acc[k];
        ((h8*)(hi + (size_t)d * H))[t] = o;
    } else {
        float4 o0; o0.x = acc[0]; o0.y = acc[1]; o0.z = acc[2]; o0.w = acc[3];
        float4 o1; o1.x = acc[4]; o1.y = acc[5]; o1.z = acc[6]; o1.w = acc[7];
        ((float4*)(out + (size_t)d * H))[2 * t] = o0;
        ((float4*)(out + (size_t)d * H))[2 * t + 1] = o1;
    }
}

// ---------------- pooling (batch is sorted), two-stage + fused mlp1 ----------------
__device__ inline int lower_bound_i(const int* b, int n, int key) {
    int lo = 0, hi = n;
    while (lo < hi) { int mid = (lo + hi) >> 1; if (b[mid] < key) lo = mid + 1; else hi = mid; }
    return lo;
}

__global__ void pool_partial(const int* __restrict__ batch, const float* __restrict__ h,
                             float* __restrict__ ppool) {
    int g = blockIdx.x / PCH, c = blockIdx.x % PCH;
    int t = threadIdx.x;   // 0..191
    int lo = lower_bound_i(batch, N_NODES, g);
    int hi = lower_bound_i(batch, N_NODES, g + 1);
    int len = hi - lo;
    int chunk = (len + PCH - 1) / PCH;
    int s = lo + c * chunk;
    int e = s + chunk; if (e > hi) e = hi;
    float4 a = {0, 0, 0, 0};
    for (int n = s; n < e; n++) {
        float4 v = ((const float4*)(h + (size_t)n * H))[t];
        a.x += v.x; a.y += v.y; a.z += v.z; a.w += v.w;
    }
    ((float4*)(ppool + (size_t)blockIdx.x * H))[t] = a;
}

__global__ __launch_bounds__(384) void pool_mlp1(const int* __restrict__ batch,
                                                 const float* __restrict__ ppool,
                                                 const float* __restrict__ wc1,
                                                 const float* __restrict__ bc1,
                                                 float* __restrict__ z) {
    __shared__ float row[H];
    int g = blockIdx.x, t = threadIdx.x;   // 384 threads
    int lo = lower_bound_i(batch, N_NODES, g);
    int hi = lower_bound_i(batch, N_NODES, g + 1);
    float inv = 1.0f / fmaxf((float)(hi - lo), 1.0f);
    for (int c0 = t; c0 < H; c0 += 384) {
        float a = 0.f;
        for (int c = 0; c < PCH; c++) a += ppool[(size_t)(g * PCH + c) * H + c0];
        row[c0] = a * inv;
    }
    __syncthreads();
    float acc = bc1[t];
    for (int k = 0; k < H; k++) acc += row[k] * wc1[(size_t)k * H2 + t];
    z[g * H2 + t] = fmaxf(acc, 0.f);
}

__global__ void mlp2(const float* __restrict__ z, const float* __restrict__ w,
                     const float* __restrict__ b, float* __restrict__ out) {
    int idx = blockIdx.x * blockDim.x + threadIdx.x;
    if (idx >= NG * NC) return;
    int gg = idx / NC, c = idx % NC;
    const float* zp = z + (size_t)gg * H2;
    float acc = b[c];
    for (int k = 0; k < H2; k++) acc += zp[k] * w[(size_t)k * NC + c];
    out[idx] = acc;
}

// ---------------- launch ----------------
extern "C" void kernel_launch(void* const* d_in, const int* in_sizes, int n_in,
                              void* d_out, int out_size, void* d_ws, size_t ws_size,
                              hipStream_t stream) {
    (void)d_ws; (void)ws_size;
    const float* x     = (const float*)d_in[0];
    const int*   ei    = (const int*)d_in[1];
    const int*   batch = (const int*)d_in[2];
    const float* w1  = (const float*)d_in[3];  const float* b1  = (const float*)d_in[4];
    const float* w2  = (const float*)d_in[5];  const float* b2  = (const float*)d_in[6];
    const float* w3  = (const float*)d_in[7];  const float* b3  = (const float*)d_in[8];
    const float* wg1 = (const float*)d_in[9];  const float* as1 = (const float*)d_in[10];
    const float* ad1 = (const float*)d_in[11]; const float* bg1 = (const float*)d_in[12];
    const float* wg2 = (const float*)d_in[13]; const float* as2 = (const float*)d_in[14];
    const float* ad2 = (const float*)d_in[15]; const float* bg2 = (const float*)d_in[16];
    const float* wc1 = (const float*)d_in[17]; const float* bc1 = (const float*)d_in[18];
    const float* wc2 = (const float*)d_in[19]; const float* bc2 = (const float*)d_in[20];

    const int* srcp = ei;            // edge_index[0]
    const int* dstp = ei + N_EDGES;  // edge_index[1]

    float *bufB, *dinv, *aS, *aD, *ppool, *zb;
    _Float16 *ah, *ch, *wh;
    int *degi, *bsum, *boff, *cursor, *rowptr, *csrsrc;
    hipGetSymbolAddress((void**)&bufB,   HIP_SYMBOL(g_bufB));
    hipGetSymbolAddress((void**)&ah,     HIP_SYMBOL(g_ah));
    hipGetSymbolAddress((void**)&ch,     HIP_SYMBOL(g_ch));
    hipGetSymbolAddress((void**)&wh,     HIP_SYMBOL(g_wh));
    hipGetSymbolAddress((void**)&dinv,   HIP_SYMBOL(g_dinv));
    hipGetSymbolAddress((void**)&degi,   HIP_SYMBOL(g_degi));
    hipGetSymbolAddress((void**)&bsum,   HIP_SYMBOL(g_bsum));
    hipGetSymbolAddress((void**)&boff,   HIP_SYMBOL(g_boff));
    hipGetSymbolAddress((void**)&cursor, HIP_SYMBOL(g_cursor));
    hipGetSymbolAddress((void**)&rowptr, HIP_SYMBOL(g_rowptr));
    hipGetSymbolAddress((void**)&csrsrc, HIP_SYMBOL(g_csrsrc));
    hipGetSymbolAddress((void**)&aS,     HIP_SYMBOL(g_aS));
    hipGetSymbolAddress((void**)&aD,     HIP_SYMBOL(g_aD));
    hipGetSymbolAddress((void**)&ppool,  HIP_SYMBOL(g_ppool));
    hipGetSymbolAddress((void**)&zb,     HIP_SYMBOL(g_zb));

    auto cdiv = [](int a, int b) { return (a + b - 1) / b; };
    int ggrid = 8 * cdiv(cdiv(N_NODES, 128), 8) * (H / 128);   // 2352
    int ngath = cdiv(N_NODES, 2);                              // 25000
    size_t HH = (size_t)H * H;

    // ---- weight transpose+cast, one launch, off the critical path ----
    split_wT4<<<cdiv(4*H*H,256),256,0,stream>>>(w2, w3, wg1, wg2, wh);

    // ---- CSR build (hierarchical scan) ----
    fill_i32<<<cdiv(N_NODES,256),256,0,stream>>>(degi, N_NODES, 0);
    count_deg<<<cdiv(N_EDGES,256),256,0,stream>>>(dstp, degi);
    scan1<<<NSB,256,0,stream>>>(degi, bsum);
    scan2<<<1,256,0,stream>>>(bsum, boff, rowptr);
    scan3<<<NSB,256,0,stream>>>(degi, boff, rowptr, cursor, dinv);
    bin_edges<<<cdiv(N_EDGES,256),256,0,stream>>>(srcp, dstp, cursor, csrsrc);

    // ---- GCN1 (K=3 GEMM stays fp32 vector math, fp16 out) ----
    gemm_k3<<<cdiv(N_NODES*H,256),256,0,stream>>>(x, w1, ch);
    gcn_gather<<<ngath,192,0,stream>>>(rowptr, csrsrc, ch, dinv, b1, ah);

    // ---- GCN2 ----
    gemm_f16<<<ggrid,256,0,stream>>>(ah, wh + 0*HH, ch, N_NODES,
                                     (const float*)nullptr, (const float*)nullptr,
                                     (float*)nullptr, (float*)nullptr);
    gcn_gather<<<ngath,192,0,stream>>>(rowptr, csrsrc, ch, dinv, b2, ah);

    // ---- GCN3 ----
    gemm_f16<<<ggrid,256,0,stream>>>(ah, wh + 1*HH, ch, N_NODES,
                                     (const float*)nullptr, (const float*)nullptr,
                                     (float*)nullptr, (float*)nullptr);
    gcn_gather<<<ngath,192,0,stream>>>(rowptr, csrsrc, ch, dinv, b3, ah);

    // ---- GAT1 (alpha fused into GEMM epilogue) ----
    gemm_f16<<<ggrid,256,0,stream>>>(ah, wh + 2*HH, ch, N_NODES, as1, ad1, aS, aD);
    gat_gather<<<ngath,192,0,stream>>>(rowptr, csrsrc, ch, aS, aD, bg1,
                                       (float*)nullptr, ah, 1);

    // ---- GAT2 (no relu; fp32 out for pooling) ----
    gemm_f16<<<ggrid,256,0,stream>>>(ah, wh + 3*HH, ch, N_NODES, as2, ad2, aS, aD);
    gat_gather<<<ngath,192,0,stream>>>(rowptr, csrsrc, ch, aS, aD, bg2,
                                       bufB, (_Float16*)nullptr, 0);

    // ---- pool (two-stage; stage-2 fused with mlp1) + classifier ----
    pool_partial<<<NG*PCH,192,0,stream>>>(batch, bufB, ppool);
    pool_mlp1<<<NG,384,0,stream>>>(batch, ppool, wc1, bc1, zb);
    mlp2<<<cdiv(NG*NC,64),64,0,stream>>>(zb, wc2, bc2, (float*)d_out);
}

// Round 16
// 1054.503 us; speedup vs baseline: 1.1307x; 1.0075x over previous
//
#include <hip/hip_runtime.h>
#include <math.h>

#define N_NODES 50000
#define N_EDGES 100000
#define H 768
#define NH 12
#define HD 64
#define NG 64
#define NC 10
#define H2 384
#define PCH 32   // pooling chunks per graph
#define NSB 196  // scan blocks = cdiv(N_NODES,256)

typedef _Float16 h8  __attribute__((ext_vector_type(8)));   // 8 fp16 (4 VGPR)
typedef _Float16 h4v __attribute__((ext_vector_type(4)));
typedef float    ffrag __attribute__((ext_vector_type(4))); // MFMA acc

// ---------------- static device scratch ----------------
__device__ float    g_bufB[(size_t)N_NODES * H];   // GAT2 fp32 out (pool input)
__device__ _Float16 g_ah[(size_t)N_NODES * H];     // GEMM input acts fp16
__device__ _Float16 g_ch[(size_t)N_NODES * H];     // GEMM output / gather input fp16
__device__ _Float16 g_wh[4 * H * H];               // 4 weights^T fp16 [N][K]
__device__ float    g_dinv[N_NODES];
__device__ int      g_degi[N_NODES];
__device__ int      g_bsum[256];
__device__ int      g_boff[256];
__device__ int      g_cursor[N_NODES];
__device__ int      g_rowptr[N_NODES + 1];
__device__ int      g_csrsrc[N_EDGES];
__device__ float    g_aS[(size_t)N_NODES * NH];
__device__ float    g_aD[(size_t)N_NODES * NH];
__device__ float    g_ppool[(size_t)NG * PCH * H]; // pooling partials (6.3 MB)
__device__ float    g_zb[NG * H2];

__device__ inline int clampi(int v, int hi) { return (v < 0) ? 0 : (v >= hi ? hi - 1 : v); }

// async global->LDS, 16B per lane: lane i writes lds_base + i*16 (wave-uniform base)
__device__ inline void gload_lds16(const _Float16* g, _Float16* s) {
    __builtin_amdgcn_global_load_lds(
        (const __attribute__((address_space(1))) void*)g,
        (__attribute__((address_space(3))) void*)s, 16, 0, 0);
}

// ---------------- CSR build ----------------
__global__ void fill_i32(int* p, int n, int v) {
    int i = blockIdx.x * blockDim.x + threadIdx.x;
    if (i < n) p[i] = v;
}

__global__ void count_deg(const int* __restrict__ dst, int* __restrict__ degi) {
    int e = blockIdx.x * blockDim.x + threadIdx.x;
    if (e < N_EDGES) atomicAdd(&degi[clampi(dst[e], N_NODES)], 1);
}

// hierarchical scan (r13-verified)
__global__ __launch_bounds__(256) void scan1(const int* __restrict__ degi, int* __restrict__ bsum) {
    __shared__ int s[256];
    int b = blockIdx.x, t = threadIdx.x;
    int idx = b * 256 + t;
    s[t] = (idx < N_NODES) ? degi[idx] : 0;
    __syncthreads();
    for (int off = 128; off > 0; off >>= 1) {
        if (t < off) s[t] += s[t + off];
        __syncthreads();
    }
    if (t == 0) bsum[b] = s[0];
}

__global__ __launch_bounds__(256) void scan2(const int* __restrict__ bsum, int* __restrict__ boff,
                                             int* __restrict__ rowptr) {
    __shared__ int s[256];
    int t = threadIdx.x;
    int v = (t < NSB) ? bsum[t] : 0;
    s[t] = v;
    __syncthreads();
    for (int off = 1; off < 256; off <<= 1) {
        int x = (t >= off) ? s[t - off] : 0;
        __syncthreads();
        s[t] += x;
        __syncthreads();
    }
    if (t < NSB) boff[t] = s[t] - v;
    if (t == NSB - 1) rowptr[N_NODES] = s[t];
}

__global__ __launch_bounds__(256) void scan3(const int* __restrict__ degi, const int* __restrict__ boff,
                                             int* __restrict__ rowptr, int* __restrict__ cursor,
                                             float* __restrict__ dinv) {
    __shared__ int s[256];
    int b = blockIdx.x, t = threadIdx.x;
    int idx = b * 256 + t;
    int v = (idx < N_NODES) ? degi[idx] : 0;
    s[t] = v;
    __syncthreads();
    for (int off = 1; off < 256; off <<= 1) {
        int x = (t >= off) ? s[t - off] : 0;
        __syncthreads();
        s[t] += x;
        __syncthreads();
    }
    if (idx < N_NODES) {
        int excl = s[t] - v + boff[b];
        rowptr[idx] = excl;
        cursor[idx] = excl;
        dinv[idx] = rsqrtf((float)v + 1.0f);   // +1 = self-loop
    }
}

__global__ void bin_edges(const int* __restrict__ src, const int* __restrict__ dst,
                          int* __restrict__ cursor, int* __restrict__ csrsrc) {
    int e = blockIdx.x * blockDim.x + threadIdx.x;
    if (e >= N_EDGES) return;
    int d = clampi(dst[e], N_NODES);
    int pos = atomicAdd(&cursor[d], 1);
    if (pos >= 0 && pos < N_EDGES) csrsrc[pos] = clampi(src[e], N_NODES);
}

// ---------------- GEMM: x@w1 (K=3), fp16 out ----------------
__global__ void gemm_k3(const float* __restrict__ x, const float* __restrict__ w,
                        _Float16* __restrict__ out) {
    int idx = blockIdx.x * blockDim.x + threadIdx.x;
    if (idx >= N_NODES * H) return;
    int n = idx / H, j = idx % H;
    float x0 = x[n*3], x1 = x[n*3+1], x2 = x[n*3+2];
    out[idx] = (_Float16)(x0 * w[j] + x1 * w[H + j] + x2 * w[2*H + j]);
}

// all 4 big weights: w[K][N] fp32 -> transposed fp16 [N][K], one launch
__global__ void split_wT4(const float* __restrict__ w2, const float* __restrict__ w3,
                          const float* __restrict__ wg1, const float* __restrict__ wg2,
                          _Float16* __restrict__ out) {
    int idx = blockIdx.x * blockDim.x + threadIdx.x;
    if (idx >= 4 * H * H) return;
    int l = idx / (H * H), r = idx % (H * H);
    const float* w = (l == 0) ? w2 : (l == 1) ? w3 : (l == 2) ? wg1 : wg2;
    int n = r % H, k = r / H;
    out[(size_t)l * H * H + (size_t)n * H + k] = (_Float16)w[(size_t)k * H + n];
}

// -- fp16 MFMA GEMM, 128x128 tile, 512 threads (8 waves), dbuf, XOR-swizzled --
// r15 evidence: conflicts 7.2e6->0 (XOR swizzle) yet dur unchanged 136 us with
// ALL pipes <20% busy -> memory-latency bound at ~10 waves/CU (Occ 30%; LDS
// appears to allocate in 64 KB granules -> 2.4 blocks/CU). Fix: same tile with
// 8 waves/block (wave tile 32x64, acc 32 VGPRs) -> ~20 waves/CU under either
// residency hypothesis. Staging 2 segs/wave. Fused-alpha: wave spans one head.
__global__ __launch_bounds__(512) void gemm_f16(const _Float16* __restrict__ a,
                                                const _Float16* __restrict__ bt,
                                                _Float16* __restrict__ C, int M,
                                                const float* __restrict__ asf,
                                                const float* __restrict__ adf,
                                                float* __restrict__ aS,
                                                float* __restrict__ aD) {
    __shared__ _Float16 sA[2][128 * 32], sB[2][128 * 32];
    int tid = threadIdx.x;
    int wave = tid >> 6, lane = tid & 63;
    int quad = lane >> 4, l16 = lane & 15;

    int id = blockIdx.x;
    int x = id & 7;
    int s = id >> 3;
    int strip = x + 8 * (s / 6);
    int colt = s % 6;
    if (strip >= (N_NODES + 127) / 128) return;
    int row0 = strip * 128, col0 = colt * 128;
    int wr = (wave >> 1) * 32, wc = (wave & 1) * 64;   // 4 row-waves x 2 col-waves

    // staging: 16 segs (0-7 = A rows, 8-15 = B rows), wave w stages 2w, 2w+1
    int rr = lane >> 2;
    int kc = (((lane & 3) ^ ((lane >> 3) & 3)) << 3);   // XOR-swizzled source chunk
    const _Float16* gptr[2];
    _Float16* sd0[2];
    _Float16* sd1[2];
    #pragma unroll
    for (int k = 0; k < 2; k++) {
        int sg = wave * 2 + k;
        int isA = (sg < 8);
        int srow = isA ? sg : sg - 8;
        int r = (isA ? row0 : col0) + srow * 16 + rr;
        if (isA && r >= M) r = M - 1;   // clamped rows feed unstored C rows
        gptr[k] = (isA ? a : bt) + (size_t)r * H + kc;
        sd0[k] = (isA ? sA[0] : sB[0]) + srow * 512;
        sd1[k] = (isA ? sA[1] : sB[1]) + srow * 512;
    }

    // fragment-read swizzle: slot = quad ^ ((l16>>1)&3), constant per lane
    int fsw = (quad ^ ((l16 >> 1) & 3)) * 8;

    ffrag acc[2][4];
    #pragma unroll
    for (int i = 0; i < 2; i++)
        #pragma unroll
        for (int j = 0; j < 4; j++) { ffrag z = {0.f, 0.f, 0.f, 0.f}; acc[i][j] = z; }

    // prologue: stage k-tile 0 into buf 0
    #pragma unroll
    for (int k = 0; k < 2; k++)
        gload_lds16(gptr[k], sd0[k]);

    #pragma unroll 1
    for (int kt = 0; kt < H / 32; kt++) {
        int cur = kt & 1;
        __syncthreads();   // buf[cur] loads complete (compiler vmcnt drain)
        if (kt + 1 < H / 32) {
            int koff = (kt + 1) * 32;
            #pragma unroll
            for (int k = 0; k < 2; k++)
                gload_lds16(gptr[k] + koff, (cur ? sd0[k] : sd1[k]));
        }

        const _Float16* pA = sA[cur];
        const _Float16* pB = sB[cur];
        h8 fa[2], fb[4];
        #pragma unroll
        for (int i = 0; i < 2; i++)
            fa[i] = *reinterpret_cast<const h8*>(&pA[(wr + i * 16 + l16) * 32 + fsw]);
        #pragma unroll
        for (int j = 0; j < 4; j++)
            fb[j] = *reinterpret_cast<const h8*>(&pB[(wc + j * 16 + l16) * 32 + fsw]);
        #pragma unroll
        for (int i = 0; i < 2; i++)
            #pragma unroll
            for (int j = 0; j < 4; j++)
                acc[i][j] = __builtin_amdgcn_mfma_f32_16x16x32_f16(fa[i], fb[j], acc[i][j], 0, 0, 0);
    }

    // epilogue: C/D layout col=lane&15, row=quad*4+reg (m89-verified); fp16 store
    #pragma unroll
    for (int i = 0; i < 2; i++)
        #pragma unroll
        for (int r = 0; r < 4; r++) {
            int row = row0 + wr + i * 16 + quad * 4 + r;
            if (row >= M) continue;
            #pragma unroll
            for (int j = 0; j < 4; j++)
                C[(size_t)row * H + col0 + wc + j * 16 + l16] = (_Float16)acc[i][j][r];
        }

    // fused GAT alpha: this wave covers one full head (64 cols) for 32 rows
    if (asf) {
        int head = (col0 + wc) >> 6;
        float as_c[4], ad_c[4];
        #pragma unroll
        for (int j = 0; j < 4; j++) {
            int col = col0 + wc + j * 16 + l16;
            as_c[j] = asf[col];
            ad_c[j] = adf[col];
        }
        #pragma unroll
        for (int i = 0; i < 2; i++)
            #pragma unroll
            for (int r = 0; r < 4; r++) {
                float ps = 0.f, pd = 0.f;
                #pragma unroll
                for (int j = 0; j < 4; j++) {
                    ps += acc[i][j][r] * as_c[j];
                    pd += acc[i][j][r] * ad_c[j];
                }
                ps += __shfl_xor(ps, 1);  pd += __shfl_xor(pd, 1);
                ps += __shfl_xor(ps, 2);  pd += __shfl_xor(pd, 2);
                ps += __shfl_xor(ps, 4);  pd += __shfl_xor(pd, 4);
                ps += __shfl_xor(ps, 8);  pd += __shfl_xor(pd, 8);
                int row = row0 + wr + i * 16 + quad * 4 + r;
                if (l16 == 0 && row < M) {
                    aS[row * NH + head] = ps;
                    aD[row * NH + head] = pd;
                }
            }
    }
}

// ------- fused GCN gather: 2 nodes/block, 16B h8 loads (r14-verified) --------
__global__ void gcn_gather(const int* __restrict__ rowptr, const int* __restrict__ csrsrc,
                           const _Float16* __restrict__ h, const float* __restrict__ dinv,
                           const float* __restrict__ bias, _Float16* __restrict__ hi) {
    int d = blockIdx.x * 2 + (threadIdx.x / 96);
    int t = threadIdx.x % 96;   // h8-chunk index (96 x 8 halves = 768)
    if (d >= N_NODES) return;
    float dd = dinv[d];
    float c = dd * dd;
    h8 v = ((const h8*)(h + (size_t)d * H))[t];
    float acc[8];
    #pragma unroll
    for (int k = 0; k < 8; k++) acc[k] = (float)v[k] * c;
    int beg = rowptr[d], end = rowptr[d + 1];
    for (int i = beg; i < end; i++) {
        int s = csrsrc[i];
        float cc = dinv[s] * dd;
        h8 u = ((const h8*)(h + (size_t)s * H))[t];
        #pragma unroll
        for (int k = 0; k < 8; k++) acc[k] += (float)u[k] * cc;
    }
    float4 b0 = ((const float4*)bias)[2 * t];
    float4 b1 = ((const float4*)bias)[2 * t + 1];
    h8 o;
    o[0] = (_Float16)fmaxf(acc[0] + b0.x, 0.f);
    o[1] = (_Float16)fmaxf(acc[1] + b0.y, 0.f);
    o[2] = (_Float16)fmaxf(acc[2] + b0.z, 0.f);
    o[3] = (_Float16)fmaxf(acc[3] + b0.w, 0.f);
    o[4] = (_Float16)fmaxf(acc[4] + b1.x, 0.f);
    o[5] = (_Float16)fmaxf(acc[5] + b1.y, 0.f);
    o[6] = (_Float16)fmaxf(acc[6] + b1.z, 0.f);
    o[7] = (_Float16)fmaxf(acc[7] + b1.w, 0.f);
    ((h8*)(hi + (size_t)d * H))[t] = o;
}

__device__ inline float lrelu(float v) { return (v > 0.f) ? v : 0.2f * v; }

// fused softmax + aggregation + bias (+relu); 2 nodes/block, 16B h8 loads.
__global__ void gat_gather(const int* __restrict__ rowptr, const int* __restrict__ csrsrc,
                           const _Float16* __restrict__ h, const float* __restrict__ aS,
                           const float* __restrict__ aD, const float* __restrict__ bias,
                           float* __restrict__ out, _Float16* __restrict__ hi, int relu) {
    int d = blockIdx.x * 2 + (threadIdx.x / 96);
    int t = threadIdx.x % 96;
    if (d >= N_NODES) return;
    int hh = t >> 3;
    int beg = rowptr[d], end = rowptr[d + 1];
    float adv = aD[d * NH + hh];
    float eself = lrelu(aS[d * NH + hh] + adv);
    float m = eself;
    for (int i = beg; i < end; i++)
        m = fmaxf(m, lrelu(aS[csrsrc[i] * NH + hh] + adv));
    float ssum = __expf(eself - m);
    for (int i = beg; i < end; i++)
        ssum += __expf(lrelu(aS[csrsrc[i] * NH + hh] + adv) - m);
    float inv = 1.0f / ssum;
    float cself = __expf(eself - m) * inv;
    h8 v = ((const h8*)(h + (size_t)d * H))[t];
    float acc[8];
    #pragma unroll
    for (int k = 0; k < 8; k++) acc[k] = (float)v[k] * cself;
    for (int i = beg; i < end; i++) {
        int s = csrsrc[i];
        float c = __expf(lrelu(aS[s * NH + hh] + adv) - m) * inv;
        h8 u = ((const h8*)(h + (size_t)s * H))[t];
        #pragma unroll
        for (int k = 0; k < 8; k++) acc[k] += (float)u[k] * c;
    }
    float4 b0 = ((const float4*)bias)[2 * t];
    float4 b1 = ((const float4*)bias)[2 * t + 1];
    acc[0] += b0.x; acc[1] += b0.y; acc[2] += b0.z; acc[3] += b0.w;
    acc[4] += b1.x; acc[5] += b1.y; acc[6] += b1.z; acc[7] += b1.w;
    if (relu) {
        #pragma unroll
        for (int k = 0; k < 8; k++) acc[k] = fmaxf(acc[k], 0.f);
    }
    if (hi) {
        h8 o;
        #pragma unroll
        for (int k = 0; k < 8; k++) o[k] = (_Float16)acc[k];
        ((h8*)(hi + (size_t)d * H))[t] = o;
    } else {
        float4 o0; o0.x = acc[0]; o0.y = acc[1]; o0.z = acc[2]; o0.w = acc[3];
        float4 o1; o1.x = acc[4]; o1.y = acc[5]; o1.z = acc[6]; o1.w = acc[7];
        ((float4*)(out + (size_t)d * H))[2 * t] = o0;
        ((float4*)(out + (size_t)d * H))[2 * t + 1] = o1;
    }
}

// ---------------- pooling (batch is sorted), two-stage + fused mlp1 ----------------
__device__ inline int lower_bound_i(const int* b, int n, int key) {
    int lo = 0, hi = n;
    while (lo < hi) { int mid = (lo + hi) >> 1; if (b[mid] < key) lo = mid + 1; else hi = mid; }
    return lo;
}

__global__ void pool_partial(const int* __restrict__ batch, const float* __restrict__ h,
                             float* __restrict__ ppool) {
    int g = blockIdx.x / PCH, c = blockIdx.x % PCH;
    int t = threadIdx.x;   // 0..191
    int lo = lower_bound_i(batch, N_NODES, g);
    int hi = lower_bound_i(batch, N_NODES, g + 1);
    int len = hi - lo;
    int chunk = (len + PCH - 1) / PCH;
    int s = lo + c * chunk;
    int e = s + chunk; if (e > hi) e = hi;
    float4 a = {0, 0, 0, 0};
    for (int n = s; n < e; n++) {
        float4 v = ((const float4*)(h + (size_t)n * H))[t];
        a.x += v.x; a.y += v.y; a.z += v.z; a.w += v.w;
    }
    ((float4*)(ppool + (size_t)blockIdx.x * H))[t] = a;
}

__global__ __launch_bounds__(384) void pool_mlp1(const int* __restrict__ batch,
                                                 const float* __restrict__ ppool,
                                                 const float* __restrict__ wc1,
                                                 const float* __restrict__ bc1,
                                                 float* __restrict__ z) {
    __shared__ float row[H];
    int g = blockIdx.x, t = threadIdx.x;   // 384 threads
    int lo = lower_bound_i(batch, N_NODES, g);
    int hi = lower_bound_i(batch, N_NODES, g + 1);
    float inv = 1.0f / fmaxf((float)(hi - lo), 1.0f);
    for (int c0 = t; c0 < H; c0 += 384) {
        float a = 0.f;
        for (int c = 0; c < PCH; c++) a += ppool[(size_t)(g * PCH + c) * H + c0];
        row[c0] = a * inv;
    }
    __syncthreads();
    float acc = bc1[t];
    for (int k = 0; k < H; k++) acc += row[k] * wc1[(size_t)k * H2 + t];
    z[g * H2 + t] = fmaxf(acc, 0.f);
}

__global__ void mlp2(const float* __restrict__ z, const float* __restrict__ w,
                     const float* __restrict__ b, float* __restrict__ out) {
    int idx = blockIdx.x * blockDim.x + threadIdx.x;
    if (idx >= NG * NC) return;
    int gg = idx / NC, c = idx % NC;
    const float* zp = z + (size_t)gg * H2;
    float acc = b[c];
    for (int k = 0; k < H2; k++) acc += zp[k] * w[(size_t)k * NC + c];
    out[idx] = acc;
}

// ---------------- launch ----------------
extern "C" void kernel_launch(void* const* d_in, const int* in_sizes, int n_in,
                              void* d_out, int out_size, void* d_ws, size_t ws_size,
                              hipStream_t stream) {
    (void)d_ws; (void)ws_size;
    const float* x     = (const float*)d_in[0];
    const int*   ei    = (const int*)d_in[1];
    const int*   batch = (const int*)d_in[2];
    const float* w1  = (const float*)d_in[3];  const float* b1  = (const float*)d_in[4];
    const float* w2  = (const float*)d_in[5];  const float* b2  = (const float*)d_in[6];
    const float* w3  = (const float*)d_in[7];  const float* b3  = (const float*)d_in[8];
    const float* wg1 = (const float*)d_in[9];  const float* as1 = (const float*)d_in[10];
    const float* ad1 = (const float*)d_in[11]; const float* bg1 = (const float*)d_in[12];
    const float* wg2 = (const float*)d_in[13]; const float* as2 = (const float*)d_in[14];
    const float* ad2 = (const float*)d_in[15]; const float* bg2 = (const float*)d_in[16];
    const float* wc1 = (const float*)d_in[17]; const float* bc1 = (const float*)d_in[18];
    const float* wc2 = (const float*)d_in[19]; const float* bc2 = (const float*)d_in[20];

    const int* srcp = ei;            // edge_index[0]
    const int* dstp = ei + N_EDGES;  // edge_index[1]

    float *bufB, *dinv, *aS, *aD, *ppool, *zb;
    _Float16 *ah, *ch, *wh;
    int *degi, *bsum, *boff, *cursor, *rowptr, *csrsrc;
    hipGetSymbolAddress((void**)&bufB,   HIP_SYMBOL(g_bufB));
    hipGetSymbolAddress((void**)&ah,     HIP_SYMBOL(g_ah));
    hipGetSymbolAddress((void**)&ch,     HIP_SYMBOL(g_ch));
    hipGetSymbolAddress((void**)&wh,     HIP_SYMBOL(g_wh));
    hipGetSymbolAddress((void**)&dinv,   HIP_SYMBOL(g_dinv));
    hipGetSymbolAddress((void**)&degi,   HIP_SYMBOL(g_degi));
    hipGetSymbolAddress((void**)&bsum,   HIP_SYMBOL(g_bsum));
    hipGetSymbolAddress((void**)&boff,   HIP_SYMBOL(g_boff));
    hipGetSymbolAddress((void**)&cursor, HIP_SYMBOL(g_cursor));
    hipGetSymbolAddress((void**)&rowptr, HIP_SYMBOL(g_rowptr));
    hipGetSymbolAddress((void**)&csrsrc, HIP_SYMBOL(g_csrsrc));
    hipGetSymbolAddress((void**)&aS,     HIP_SYMBOL(g_aS));
    hipGetSymbolAddress((void**)&aD,     HIP_SYMBOL(g_aD));
    hipGetSymbolAddress((void**)&ppool,  HIP_SYMBOL(g_ppool));
    hipGetSymbolAddress((void**)&zb,     HIP_SYMBOL(g_zb));

    auto cdiv = [](int a, int b) { return (a + b - 1) / b; };
    int ggrid = 8 * cdiv(cdiv(N_NODES, 128), 8) * (H / 128);   // 2352
    int ngath = cdiv(N_NODES, 2);                              // 25000
    size_t HH = (size_t)H * H;

    // ---- weight transpose+cast, one launch, off the critical path ----
    split_wT4<<<cdiv(4*H*H,256),256,0,stream>>>(w2, w3, wg1, wg2, wh);

    // ---- CSR build (hierarchical scan) ----
    fill_i32<<<cdiv(N_NODES,256),256,0,stream>>>(degi, N_NODES, 0);
    count_deg<<<cdiv(N_EDGES,256),256,0,stream>>>(dstp, degi);
    scan1<<<NSB,256,0,stream>>>(degi, bsum);
    scan2<<<1,256,0,stream>>>(bsum, boff, rowptr);
    scan3<<<NSB,256,0,stream>>>(degi, boff, rowptr, cursor, dinv);
    bin_edges<<<cdiv(N_EDGES,256),256,0,stream>>>(srcp, dstp, cursor, csrsrc);

    // ---- GCN1 (K=3 GEMM stays fp32 vector math, fp16 out) ----
    gemm_k3<<<cdiv(N_NODES*H,256),256,0,stream>>>(x, w1, ch);
    gcn_gather<<<ngath,192,0,stream>>>(rowptr, csrsrc, ch, dinv, b1, ah);

    // ---- GCN2 ----
    gemm_f16<<<ggrid,512,0,stream>>>(ah, wh + 0*HH, ch, N_NODES,
                                     (const float*)nullptr, (const float*)nullptr,
                                     (float*)nullptr, (float*)nullptr);
    gcn_gather<<<ngath,192,0,stream>>>(rowptr, csrsrc, ch, dinv, b2, ah);

    // ---- GCN3 ----
    gemm_f16<<<ggrid,512,0,stream>>>(ah, wh + 1*HH, ch, N_NODES,
                                     (const float*)nullptr, (const float*)nullptr,
                                     (float*)nullptr, (float*)nullptr);
    gcn_gather<<<ngath,192,0,stream>>>(rowptr, csrsrc, ch, dinv, b3, ah);

    // ---- GAT1 (alpha fused into GEMM epilogue) ----
    gemm_f16<<<ggrid,512,0,stream>>>(ah, wh + 2*HH, ch, N_NODES, as1, ad1, aS, aD);
    gat_gather<<<ngath,192,0,stream>>>(rowptr, csrsrc, ch, aS, aD, bg1,
                                       (float*)nullptr, ah, 1);

    // ---- GAT2 (no relu; fp32 out for pooling) ----
    gemm_f16<<<ggrid,512,0,stream>>>(ah, wh + 3*HH, ch, N_NODES, as2, ad2, aS, aD);
    gat_gather<<<ngath,192,0,stream>>>(rowptr, csrsrc, ch, aS, aD, bg2,
                                       bufB, (_Float16*)nullptr, 0);

    // ---- pool (two-stage; stage-2 fused with mlp1) + classifier ----
    pool_partial<<<NG*PCH,192,0,stream>>>(batch, bufB, ppool);
    pool_mlp1<<<NG,384,0,stream>>>(batch, ppool, wc1, bc1, zb);
    mlp2<<<cdiv(NG*NC,64),64,0,stream>>>(zb, wc2, bc2, (float*)d_out);
}

// Round 17
// 930.308 us; speedup vs baseline: 1.2817x; 1.1335x over previous
//
#include <hip/hip_runtime.h>
#include <math.h>

#define N_NODES 50000
#define N_EDGES 100000
#define H 768
#define NH 12
#define HD 64
#define NG 64
#define NC 10
#define H2 384
#define PCH 32   // pooling chunks per graph
#define NSB 196  // scan blocks = cdiv(N_NODES,256)

typedef _Float16 h8  __attribute__((ext_vector_type(8)));   // 8 fp16 (4 VGPR)
typedef _Float16 h4v __attribute__((ext_vector_type(4)));
typedef float    ffrag __attribute__((ext_vector_type(4))); // MFMA acc

// ---------------- static device scratch ----------------
__device__ _Float16 g_ah[(size_t)N_NODES * H];     // GEMM input acts fp16
__device__ _Float16 g_ch[(size_t)N_NODES * H];     // GEMM output / gather input fp16
__device__ _Float16 g_wh[4 * H * H];               // 4 weights^T fp16 [N][K]
__device__ float    g_dinv[N_NODES];
__device__ int      g_degi[N_NODES];
__device__ int      g_bsum[256];
__device__ int      g_boff[256];
__device__ int      g_cursor[N_NODES];
__device__ int      g_rowptr[N_NODES + 1];
__device__ int      g_csrsrc[N_EDGES];
__device__ float    g_aS[(size_t)N_NODES * NH];
__device__ float    g_aD[(size_t)N_NODES * NH];
__device__ float    g_ppool[(size_t)NG * PCH * H]; // pooling partials (6.3 MB)
__device__ float    g_zb[NG * H2];

__device__ inline int clampi(int v, int hi) { return (v < 0) ? 0 : (v >= hi ? hi - 1 : v); }

// async global->LDS, 16B per lane: lane i writes lds_base + i*16 (wave-uniform base)
__device__ inline void gload_lds16(const _Float16* g, _Float16* s) {
    __builtin_amdgcn_global_load_lds(
        (const __attribute__((address_space(1))) void*)g,
        (__attribute__((address_space(3))) void*)s, 16, 0, 0);
}

// ---------------- CSR build ----------------
__global__ void fill_i32(int* p, int n, int v) {
    int i = blockIdx.x * blockDim.x + threadIdx.x;
    if (i < n) p[i] = v;
}

__global__ void count_deg(const int* __restrict__ dst, int* __restrict__ degi) {
    int e = blockIdx.x * blockDim.x + threadIdx.x;
    if (e < N_EDGES) atomicAdd(&degi[clampi(dst[e], N_NODES)], 1);
}

// hierarchical scan (r13-verified)
__global__ __launch_bounds__(256) void scan1(const int* __restrict__ degi, int* __restrict__ bsum) {
    __shared__ int s[256];
    int b = blockIdx.x, t = threadIdx.x;
    int idx = b * 256 + t;
    s[t] = (idx < N_NODES) ? degi[idx] : 0;
    __syncthreads();
    for (int off = 128; off > 0; off >>= 1) {
        if (t < off) s[t] += s[t + off];
        __syncthreads();
    }
    if (t == 0) bsum[b] = s[0];
}

__global__ __launch_bounds__(256) void scan2(const int* __restrict__ bsum, int* __restrict__ boff,
                                             int* __restrict__ rowptr) {
    __shared__ int s[256];
    int t = threadIdx.x;
    int v = (t < NSB) ? bsum[t] : 0;
    s[t] = v;
    __syncthreads();
    for (int off = 1; off < 256; off <<= 1) {
        int x = (t >= off) ? s[t - off] : 0;
        __syncthreads();
        s[t] += x;
        __syncthreads();
    }
    if (t < NSB) boff[t] = s[t] - v;
    if (t == NSB - 1) rowptr[N_NODES] = s[t];
}

__global__ __launch_bounds__(256) void scan3(const int* __restrict__ degi, const int* __restrict__ boff,
                                             int* __restrict__ rowptr, int* __restrict__ cursor,
                                             float* __restrict__ dinv) {
    __shared__ int s[256];
    int b = blockIdx.x, t = threadIdx.x;
    int idx = b * 256 + t;
    int v = (idx < N_NODES) ? degi[idx] : 0;
    s[t] = v;
    __syncthreads();
    for (int off = 1; off < 256; off <<= 1) {
        int x = (t >= off) ? s[t - off] : 0;
        __syncthreads();
        s[t] += x;
        __syncthreads();
    }
    if (idx < N_NODES) {
        int excl = s[t] - v + boff[b];
        rowptr[idx] = excl;
        cursor[idx] = excl;
        dinv[idx] = rsqrtf((float)v + 1.0f);   // +1 = self-loop
    }
}

__global__ void bin_edges(const int* __restrict__ src, const int* __restrict__ dst,
                          int* __restrict__ cursor, int* __restrict__ csrsrc) {
    int e = blockIdx.x * blockDim.x + threadIdx.x;
    if (e >= N_EDGES) return;
    int d = clampi(dst[e], N_NODES);
    int pos = atomicAdd(&cursor[d], 1);
    if (pos >= 0 && pos < N_EDGES) csrsrc[pos] = clampi(src[e], N_NODES);
}

// all 4 big weights: w[K][N] fp32 -> transposed fp16 [N][K], one launch
__global__ void split_wT4(const float* __restrict__ w2, const float* __restrict__ w3,
                          const float* __restrict__ wg1, const float* __restrict__ wg2,
                          _Float16* __restrict__ out) {
    int idx = blockIdx.x * blockDim.x + threadIdx.x;
    if (idx >= 4 * H * H) return;
    int l = idx / (H * H), r = idx % (H * H);
    const float* w = (l == 0) ? w2 : (l == 1) ? w3 : (l == 2) ? wg1 : wg2;
    int n = r % H, k = r / H;
    out[(size_t)l * H * H + (size_t)n * H + k] = (_Float16)w[(size_t)k * H + n];
}

// ---- fused GCN1: aggregate x (3-dim!) then matvec w1 + bias + relu + fp16 ----
// A_norm·(x@w1) == (A_norm·x)@w1 -- aggregating the 3-dim input first turns
// layer 1's 230 MB H-row gather into 12 B/node reads (x is 600 KB, L2-resident)
// + a 3x768 matvec against L1-resident w1. Deletes gemm_k3 entirely.
__global__ void gcn1_fused(const int* __restrict__ rowptr, const int* __restrict__ csrsrc,
                           const float* __restrict__ x, const float* __restrict__ dinv,
                           const float* __restrict__ w1, const float* __restrict__ b1,
                           _Float16* __restrict__ hi) {
    int d = blockIdx.x * 2 + (threadIdx.x / 96);
    int t = threadIdx.x % 96;
    if (d >= N_NODES) return;
    float dd = dinv[d];
    float c = dd * dd;
    float s0 = x[d*3] * c, s1 = x[d*3+1] * c, s2 = x[d*3+2] * c;
    int beg = rowptr[d], end = rowptr[d + 1];
    for (int i = beg; i < end; i++) {
        int s = csrsrc[i];
        float cc = dinv[s] * dd;
        s0 += x[s*3] * cc; s1 += x[s*3+1] * cc; s2 += x[s*3+2] * cc;
    }
    int j0 = t * 8;
    h8 o;
    #pragma unroll
    for (int k = 0; k < 8; k++) {
        int j = j0 + k;
        float v = s0 * w1[j] + s1 * w1[H + j] + s2 * w1[2*H + j] + b1[j];
        o[k] = (_Float16)fmaxf(v, 0.f);
    }
    ((h8*)(hi + (size_t)d * H))[t] = o;
}

// -- fp16 MFMA GEMM, 128x128 tile, 512 threads (8 waves), dbuf, XOR-swizzled --
// r16: 512-thr raised Occ 30->59% for +5% (129.7 us). Four structural attacks
// (dbuf-64K r7, B-bypass r8, 64-tile r14, 8-wave r16) confirm ~130 us is the
// vmcnt(0)+s_barrier drain plateau of this K-loop at HIP level. GEMM frozen.
__global__ __launch_bounds__(512) void gemm_f16(const _Float16* __restrict__ a,
                                                const _Float16* __restrict__ bt,
                                                _Float16* __restrict__ C, int M,
                                                const float* __restrict__ asf,
                                                const float* __restrict__ adf,
                                                float* __restrict__ aS,
                                                float* __restrict__ aD) {
    __shared__ _Float16 sA[2][128 * 32], sB[2][128 * 32];
    int tid = threadIdx.x;
    int wave = tid >> 6, lane = tid & 63;
    int quad = lane >> 4, l16 = lane & 15;

    int id = blockIdx.x;
    int x = id & 7;
    int s = id >> 3;
    int strip = x + 8 * (s / 6);
    int colt = s % 6;
    if (strip >= (N_NODES + 127) / 128) return;
    int row0 = strip * 128, col0 = colt * 128;
    int wr = (wave >> 1) * 32, wc = (wave & 1) * 64;   // 4 row-waves x 2 col-waves

    // staging: 16 segs (0-7 = A rows, 8-15 = B rows), wave w stages 2w, 2w+1
    int rr = lane >> 2;
    int kc = (((lane & 3) ^ ((lane >> 3) & 3)) << 3);   // XOR-swizzled source chunk
    const _Float16* gptr[2];
    _Float16* sd0[2];
    _Float16* sd1[2];
    #pragma unroll
    for (int k = 0; k < 2; k++) {
        int sg = wave * 2 + k;
        int isA = (sg < 8);
        int srow = isA ? sg : sg - 8;
        int r = (isA ? row0 : col0) + srow * 16 + rr;
        if (isA && r >= M) r = M - 1;   // clamped rows feed unstored C rows
        gptr[k] = (isA ? a : bt) + (size_t)r * H + kc;
        sd0[k] = (isA ? sA[0] : sB[0]) + srow * 512;
        sd1[k] = (isA ? sA[1] : sB[1]) + srow * 512;
    }

    // fragment-read swizzle: slot = quad ^ ((l16>>1)&3), constant per lane
    int fsw = (quad ^ ((l16 >> 1) & 3)) * 8;

    ffrag acc[2][4];
    #pragma unroll
    for (int i = 0; i < 2; i++)
        #pragma unroll
        for (int j = 0; j < 4; j++) { ffrag z = {0.f, 0.f, 0.f, 0.f}; acc[i][j] = z; }

    // prologue: stage k-tile 0 into buf 0
    #pragma unroll
    for (int k = 0; k < 2; k++)
        gload_lds16(gptr[k], sd0[k]);

    #pragma unroll 1
    for (int kt = 0; kt < H / 32; kt++) {
        int cur = kt & 1;
        __syncthreads();   // buf[cur] loads complete (compiler vmcnt drain)
        if (kt + 1 < H / 32) {
            int koff = (kt + 1) * 32;
            #pragma unroll
            for (int k = 0; k < 2; k++)
                gload_lds16(gptr[k] + koff, (cur ? sd0[k] : sd1[k]));
        }

        const _Float16* pA = sA[cur];
        const _Float16* pB = sB[cur];
        h8 fa[2], fb[4];
        #pragma unroll
        for (int i = 0; i < 2; i++)
            fa[i] = *reinterpret_cast<const h8*>(&pA[(wr + i * 16 + l16) * 32 + fsw]);
        #pragma unroll
        for (int j = 0; j < 4; j++)
            fb[j] = *reinterpret_cast<const h8*>(&pB[(wc + j * 16 + l16) * 32 + fsw]);
        #pragma unroll
        for (int i = 0; i < 2; i++)
            #pragma unroll
            for (int j = 0; j < 4; j++)
                acc[i][j] = __builtin_amdgcn_mfma_f32_16x16x32_f16(fa[i], fb[j], acc[i][j], 0, 0, 0);
    }

    // epilogue: C/D layout col=lane&15, row=quad*4+reg (m89-verified); fp16 store
    #pragma unroll
    for (int i = 0; i < 2; i++)
        #pragma unroll
        for (int r = 0; r < 4; r++) {
            int row = row0 + wr + i * 16 + quad * 4 + r;
            if (row >= M) continue;
            #pragma unroll
            for (int j = 0; j < 4; j++)
                C[(size_t)row * H + col0 + wc + j * 16 + l16] = (_Float16)acc[i][j][r];
        }

    // fused GAT alpha: this wave covers one full head (64 cols) for 32 rows
    if (asf) {
        int head = (col0 + wc) >> 6;
        float as_c[4], ad_c[4];
        #pragma unroll
        for (int j = 0; j < 4; j++) {
            int col = col0 + wc + j * 16 + l16;
            as_c[j] = asf[col];
            ad_c[j] = adf[col];
        }
        #pragma unroll
        for (int i = 0; i < 2; i++)
            #pragma unroll
            for (int r = 0; r < 4; r++) {
                float ps = 0.f, pd = 0.f;
                #pragma unroll
                for (int j = 0; j < 4; j++) {
                    ps += acc[i][j][r] * as_c[j];
                    pd += acc[i][j][r] * ad_c[j];
                }
                ps += __shfl_xor(ps, 1);  pd += __shfl_xor(pd, 1);
                ps += __shfl_xor(ps, 2);  pd += __shfl_xor(pd, 2);
                ps += __shfl_xor(ps, 4);  pd += __shfl_xor(pd, 4);
                ps += __shfl_xor(ps, 8);  pd += __shfl_xor(pd, 8);
                int row = row0 + wr + i * 16 + quad * 4 + r;
                if (l16 == 0 && row < M) {
                    aS[row * NH + head] = ps;
                    aD[row * NH + head] = pd;
                }
            }
    }
}

// ------- fused GCN gather: 2 nodes/block, 16B h8 loads (r14-verified) --------
__global__ void gcn_gather(const int* __restrict__ rowptr, const int* __restrict__ csrsrc,
                           const _Float16* __restrict__ h, const float* __restrict__ dinv,
                           const float* __restrict__ bias, _Float16* __restrict__ hi) {
    int d = blockIdx.x * 2 + (threadIdx.x / 96);
    int t = threadIdx.x % 96;   // h8-chunk index (96 x 8 halves = 768)
    if (d >= N_NODES) return;
    float dd = dinv[d];
    float c = dd * dd;
    h8 v = ((const h8*)(h + (size_t)d * H))[t];
    float acc[8];
    #pragma unroll
    for (int k = 0; k < 8; k++) acc[k] = (float)v[k] * c;
    int beg = rowptr[d], end = rowptr[d + 1];
    for (int i = beg; i < end; i++) {
        int s = csrsrc[i];
        float cc = dinv[s] * dd;
        h8 u = ((const h8*)(h + (size_t)s * H))[t];
        #pragma unroll
        for (int k = 0; k < 8; k++) acc[k] += (float)u[k] * cc;
    }
    float4 b0 = ((const float4*)bias)[2 * t];
    float4 b1 = ((const float4*)bias)[2 * t + 1];
    h8 o;
    o[0] = (_Float16)fmaxf(acc[0] + b0.x, 0.f);
    o[1] = (_Float16)fmaxf(acc[1] + b0.y, 0.f);
    o[2] = (_Float16)fmaxf(acc[2] + b0.z, 0.f);
    o[3] = (_Float16)fmaxf(acc[3] + b0.w, 0.f);
    o[4] = (_Float16)fmaxf(acc[4] + b1.x, 0.f);
    o[5] = (_Float16)fmaxf(acc[5] + b1.y, 0.f);
    o[6] = (_Float16)fmaxf(acc[6] + b1.z, 0.f);
    o[7] = (_Float16)fmaxf(acc[7] + b1.w, 0.f);
    ((h8*)(hi + (size_t)d * H))[t] = o;
}

__device__ inline float lrelu(float v) { return (v > 0.f) ? v : 0.2f * v; }

// fused softmax + aggregation + bias (+relu); 2 nodes/block, 16B h8 loads.
// always writes fp16 (r17: GAT2 pools from fp16 too).
__global__ void gat_gather(const int* __restrict__ rowptr, const int* __restrict__ csrsrc,
                           const _Float16* __restrict__ h, const float* __restrict__ aS,
                           const float* __restrict__ aD, const float* __restrict__ bias,
                           _Float16* __restrict__ hi, int relu) {
    int d = blockIdx.x * 2 + (threadIdx.x / 96);
    int t = threadIdx.x % 96;
    if (d >= N_NODES) return;
    int hh = t >> 3;
    int beg = rowptr[d], end = rowptr[d + 1];
    float adv = aD[d * NH + hh];
    float eself = lrelu(aS[d * NH + hh] + adv);
    float m = eself;
    for (int i = beg; i < end; i++)
        m = fmaxf(m, lrelu(aS[csrsrc[i] * NH + hh] + adv));
    float ssum = __expf(eself - m);
    for (int i = beg; i < end; i++)
        ssum += __expf(lrelu(aS[csrsrc[i] * NH + hh] + adv) - m);
    float inv = 1.0f / ssum;
    float cself = __expf(eself - m) * inv;
    h8 v = ((const h8*)(h + (size_t)d * H))[t];
    float acc[8];
    #pragma unroll
    for (int k = 0; k < 8; k++) acc[k] = (float)v[k] * cself;
    for (int i = beg; i < end; i++) {
        int s = csrsrc[i];
        float c = __expf(lrelu(aS[s * NH + hh] + adv) - m) * inv;
        h8 u = ((const h8*)(h + (size_t)s * H))[t];
        #pragma unroll
        for (int k = 0; k < 8; k++) acc[k] += (float)u[k] * c;
    }
    float4 b0 = ((const float4*)bias)[2 * t];
    float4 b1 = ((const float4*)bias)[2 * t + 1];
    acc[0] += b0.x; acc[1] += b0.y; acc[2] += b0.z; acc[3] += b0.w;
    acc[4] += b1.x; acc[5] += b1.y; acc[6] += b1.z; acc[7] += b1.w;
    if (relu) {
        #pragma unroll
        for (int k = 0; k < 8; k++) acc[k] = fmaxf(acc[k], 0.f);
    }
    h8 o;
    #pragma unroll
    for (int k = 0; k < 8; k++) o[k] = (_Float16)acc[k];
    ((h8*)(hi + (size_t)d * H))[t] = o;
}

// ---------------- pooling (batch is sorted), two-stage + fused mlp1 ----------------
__device__ inline int lower_bound_i(const int* b, int n, int key) {
    int lo = 0, hi = n;
    while (lo < hi) { int mid = (lo + hi) >> 1; if (b[mid] < key) lo = mid + 1; else hi = mid; }
    return lo;
}

// stage 1 reads fp16 now (r17) -- half the traffic of the old fp32 path
__global__ void pool_partial(const int* __restrict__ batch, const _Float16* __restrict__ h,
                             float* __restrict__ ppool) {
    int g = blockIdx.x / PCH, c = blockIdx.x % PCH;
    int t = threadIdx.x;   // 0..191, h4v chunks
    int lo = lower_bound_i(batch, N_NODES, g);
    int hi = lower_bound_i(batch, N_NODES, g + 1);
    int len = hi - lo;
    int chunk = (len + PCH - 1) / PCH;
    int s = lo + c * chunk;
    int e = s + chunk; if (e > hi) e = hi;
    float4 a = {0, 0, 0, 0};
    for (int n = s; n < e; n++) {
        h4v v = ((const h4v*)(h + (size_t)n * H))[t];
        a.x += (float)v[0]; a.y += (float)v[1]; a.z += (float)v[2]; a.w += (float)v[3];
    }
    ((float4*)(ppool + (size_t)blockIdx.x * H))[t] = a;
}

__global__ __launch_bounds__(384) void pool_mlp1(const int* __restrict__ batch,
                                                 const float* __restrict__ ppool,
                                                 const float* __restrict__ wc1,
                                                 const float* __restrict__ bc1,
                                                 float* __restrict__ z) {
    __shared__ float row[H];
    int g = blockIdx.x, t = threadIdx.x;   // 384 threads
    int lo = lower_bound_i(batch, N_NODES, g);
    int hi = lower_bound_i(batch, N_NODES, g + 1);
    float inv = 1.0f / fmaxf((float)(hi - lo), 1.0f);
    for (int c0 = t; c0 < H; c0 += 384) {
        float a = 0.f;
        for (int c = 0; c < PCH; c++) a += ppool[(size_t)(g * PCH + c) * H + c0];
        row[c0] = a * inv;
    }
    __syncthreads();
    float acc = bc1[t];
    for (int k = 0; k < H; k++) acc += row[k] * wc1[(size_t)k * H2 + t];
    z[g * H2 + t] = fmaxf(acc, 0.f);
}

__global__ void mlp2(const float* __restrict__ z, const float* __restrict__ w,
                     const float* __restrict__ b, float* __restrict__ out) {
    int idx = blockIdx.x * blockDim.x + threadIdx.x;
    if (idx >= NG * NC) return;
    int gg = idx / NC, c = idx % NC;
    const float* zp = z + (size_t)gg * H2;
    float acc = b[c];
    for (int k = 0; k < H2; k++) acc += zp[k] * w[(size_t)k * NC + c];
    out[idx] = acc;
}

// ---------------- launch ----------------
extern "C" void kernel_launch(void* const* d_in, const int* in_sizes, int n_in,
                              void* d_out, int out_size, void* d_ws, size_t ws_size,
                              hipStream_t stream) {
    (void)d_ws; (void)ws_size;
    const float* x     = (const float*)d_in[0];
    const int*   ei    = (const int*)d_in[1];
    const int*   batch = (const int*)d_in[2];
    const float* w1  = (const float*)d_in[3];  const float* b1  = (const float*)d_in[4];
    const float* w2  = (const float*)d_in[5];  const float* b2  = (const float*)d_in[6];
    const float* w3  = (const float*)d_in[7];  const float* b3  = (const float*)d_in[8];
    const float* wg1 = (const float*)d_in[9];  const float* as1 = (const float*)d_in[10];
    const float* ad1 = (const float*)d_in[11]; const float* bg1 = (const float*)d_in[12];
    const float* wg2 = (const float*)d_in[13]; const float* as2 = (const float*)d_in[14];
    const float* ad2 = (const float*)d_in[15]; const float* bg2 = (const float*)d_in[16];
    const float* wc1 = (const float*)d_in[17]; const float* bc1 = (const float*)d_in[18];
    const float* wc2 = (const float*)d_in[19]; const float* bc2 = (const float*)d_in[20];

    const int* srcp = ei;            // edge_index[0]
    const int* dstp = ei + N_EDGES;  // edge_index[1]

    float *dinv, *aS, *aD, *ppool, *zb;
    _Float16 *ah, *ch, *wh;
    int *degi, *bsum, *boff, *cursor, *rowptr, *csrsrc;
    hipGetSymbolAddress((void**)&ah,     HIP_SYMBOL(g_ah));
    hipGetSymbolAddress((void**)&ch,     HIP_SYMBOL(g_ch));
    hipGetSymbolAddress((void**)&wh,     HIP_SYMBOL(g_wh));
    hipGetSymbolAddress((void**)&dinv,   HIP_SYMBOL(g_dinv));
    hipGetSymbolAddress((void**)&degi,   HIP_SYMBOL(g_degi));
    hipGetSymbolAddress((void**)&bsum,   HIP_SYMBOL(g_bsum));
    hipGetSymbolAddress((void**)&boff,   HIP_SYMBOL(g_boff));
    hipGetSymbolAddress((void**)&cursor, HIP_SYMBOL(g_cursor));
    hipGetSymbolAddress((void**)&rowptr, HIP_SYMBOL(g_rowptr));
    hipGetSymbolAddress((void**)&csrsrc, HIP_SYMBOL(g_csrsrc));
    hipGetSymbolAddress((void**)&aS,     HIP_SYMBOL(g_aS));
    hipGetSymbolAddress((void**)&aD,     HIP_SYMBOL(g_aD));
    hipGetSymbolAddress((void**)&ppool,  HIP_SYMBOL(g_ppool));
    hipGetSymbolAddress((void**)&zb,     HIP_SYMBOL(g_zb));

    auto cdiv = [](int a, int b) { return (a + b - 1) / b; };
    int ggrid = 8 * cdiv(cdiv(N_NODES, 128), 8) * (H / 128);   // 2352
    int ngath = cdiv(N_NODES, 2);                              // 25000
    size_t HH = (size_t)H * H;

    // ---- weight transpose+cast, one launch, off the critical path ----
    split_wT4<<<cdiv(4*H*H,256),256,0,stream>>>(w2, w3, wg1, wg2, wh);

    // ---- CSR build (hierarchical scan) ----
    fill_i32<<<cdiv(N_NODES,256),256,0,stream>>>(degi, N_NODES, 0);
    count_deg<<<cdiv(N_EDGES,256),256,0,stream>>>(dstp, degi);
    scan1<<<NSB,256,0,stream>>>(degi, bsum);
    scan2<<<1,256,0,stream>>>(bsum, boff, rowptr);
    scan3<<<NSB,256,0,stream>>>(degi, boff, rowptr, cursor, dinv);
    bin_edges<<<cdiv(N_EDGES,256),256,0,stream>>>(srcp, dstp, cursor, csrsrc);

    // ---- GCN1: aggregate-first (3-dim) + matvec, single kernel ----
    gcn1_fused<<<ngath,192,0,stream>>>(rowptr, csrsrc, x, dinv, w1, b1, ah);

    // ---- GCN2 ----
    gemm_f16<<<ggrid,512,0,stream>>>(ah, wh + 0*HH, ch, N_NODES,
                                     (const float*)nullptr, (const float*)nullptr,
                                     (float*)nullptr, (float*)nullptr);
    gcn_gather<<<ngath,192,0,stream>>>(rowptr, csrsrc, ch, dinv, b2, ah);

    // ---- GCN3 ----
    gemm_f16<<<ggrid,512,0,stream>>>(ah, wh + 1*HH, ch, N_NODES,
                                     (const float*)nullptr, (const float*)nullptr,
                                     (float*)nullptr, (float*)nullptr);
    gcn_gather<<<ngath,192,0,stream>>>(rowptr, csrsrc, ch, dinv, b3, ah);

    // ---- GAT1 (alpha fused into GEMM epilogue) ----
    gemm_f16<<<ggrid,512,0,stream>>>(ah, wh + 2*HH, ch, N_NODES, as1, ad1, aS, aD);
    gat_gather<<<ngath,192,0,stream>>>(rowptr, csrsrc, ch, aS, aD, bg1, ah, 1);

    // ---- GAT2 (no relu; fp16 out -> fp16 pooling) ----
    gemm_f16<<<ggrid,512,0,stream>>>(ah, wh + 3*HH, ch, N_NODES, as2, ad2, aS, aD);
    gat_gather<<<ngath,192,0,stream>>>(rowptr, csrsrc, ch, aS, aD, bg2, ah, 0);

    // ---- pool (two-stage; stage-2 fused with mlp1) + classifier ----
    pool_partial<<<NG*PCH,192,0,stream>>>(batch, ah, ppool);
    pool_mlp1<<<NG,384,0,stream>>>(batch, ppool, wc1, bc1, zb);
    mlp2<<<cdiv(NG*NC,64),64,0,stream>>>(zb, wc2, bc2, (float*)d_out);
}

// Round 18
// 906.609 us; speedup vs baseline: 1.3152x; 1.0261x over previous
//
#include <hip/hip_runtime.h>
#include <math.h>

#define N_NODES 50000
#define N_EDGES 100000
#define H 768
#define NH 12
#define HD 64
#define NG 64
#define NC 10
#define H2 384
#define PCH 32   // pooling chunks per graph
#define NSB 196  // scan blocks = cdiv(N_NODES,256)

typedef _Float16 h8  __attribute__((ext_vector_type(8)));   // 8 fp16 (4 VGPR)
typedef _Float16 h4v __attribute__((ext_vector_type(4)));
typedef float    ffrag __attribute__((ext_vector_type(4))); // MFMA acc

// ---------------- static device scratch ----------------
__device__ _Float16 g_ah[(size_t)N_NODES * H];     // GEMM input acts fp16
__device__ _Float16 g_ch[(size_t)N_NODES * H];     // GEMM output / gather input fp16
__device__ _Float16 g_wh[4 * H * H];               // 4 weights^T fp16 [N][K]
__device__ float    g_dinv[N_NODES];
__device__ int      g_degi[N_NODES];
__device__ int      g_bsum[256];
__device__ int      g_boff[256];
__device__ int      g_cursor[N_NODES];
__device__ int      g_rowptr[N_NODES + 1];
__device__ int      g_csrsrc[N_EDGES];
__device__ float    g_aS[(size_t)N_NODES * NH];
__device__ float    g_aD[(size_t)N_NODES * NH];
__device__ float    g_selfc[(size_t)N_NODES * NH]; // GAT self-coefficient
__device__ float    g_coef[(size_t)N_EDGES * NH];  // GAT per-edge coefficient (4.8 MB)
__device__ float    g_ppool[(size_t)NG * PCH * H]; // pooling partials (6.3 MB)
__device__ float    g_zb[NG * H2];

__device__ inline int clampi(int v, int hi) { return (v < 0) ? 0 : (v >= hi ? hi - 1 : v); }

// async global->LDS, 16B per lane: lane i writes lds_base + i*16 (wave-uniform base)
__device__ inline void gload_lds16(const _Float16* g, _Float16* s) {
    __builtin_amdgcn_global_load_lds(
        (const __attribute__((address_space(1))) void*)g,
        (__attribute__((address_space(3))) void*)s, 16, 0, 0);
}

// ---------------- CSR build ----------------
__global__ void fill_i32(int* p, int n, int v) {
    int i = blockIdx.x * blockDim.x + threadIdx.x;
    if (i < n) p[i] = v;
}

__global__ void count_deg(const int* __restrict__ dst, int* __restrict__ degi) {
    int e = blockIdx.x * blockDim.x + threadIdx.x;
    if (e < N_EDGES) atomicAdd(&degi[clampi(dst[e], N_NODES)], 1);
}

// hierarchical scan (r13-verified)
__global__ __launch_bounds__(256) void scan1(const int* __restrict__ degi, int* __restrict__ bsum) {
    __shared__ int s[256];
    int b = blockIdx.x, t = threadIdx.x;
    int idx = b * 256 + t;
    s[t] = (idx < N_NODES) ? degi[idx] : 0;
    __syncthreads();
    for (int off = 128; off > 0; off >>= 1) {
        if (t < off) s[t] += s[t + off];
        __syncthreads();
    }
    if (t == 0) bsum[b] = s[0];
}

__global__ __launch_bounds__(256) void scan2(const int* __restrict__ bsum, int* __restrict__ boff,
                                             int* __restrict__ rowptr) {
    __shared__ int s[256];
    int t = threadIdx.x;
    int v = (t < NSB) ? bsum[t] : 0;
    s[t] = v;
    __syncthreads();
    for (int off = 1; off < 256; off <<= 1) {
        int x = (t >= off) ? s[t - off] : 0;
        __syncthreads();
        s[t] += x;
        __syncthreads();
    }
    if (t < NSB) boff[t] = s[t] - v;
    if (t == NSB - 1) rowptr[N_NODES] = s[t];
}

__global__ __launch_bounds__(256) void scan3(const int* __restrict__ degi, const int* __restrict__ boff,
                                             int* __restrict__ rowptr, int* __restrict__ cursor,
                                             float* __restrict__ dinv) {
    __shared__ int s[256];
    int b = blockIdx.x, t = threadIdx.x;
    int idx = b * 256 + t;
    int v = (idx < N_NODES) ? degi[idx] : 0;
    s[t] = v;
    __syncthreads();
    for (int off = 1; off < 256; off <<= 1) {
        int x = (t >= off) ? s[t - off] : 0;
        __syncthreads();
        s[t] += x;
        __syncthreads();
    }
    if (idx < N_NODES) {
        int excl = s[t] - v + boff[b];
        rowptr[idx] = excl;
        cursor[idx] = excl;
        dinv[idx] = rsqrtf((float)v + 1.0f);   // +1 = self-loop
    }
}

__global__ void bin_edges(const int* __restrict__ src, const int* __restrict__ dst,
                          int* __restrict__ cursor, int* __restrict__ csrsrc) {
    int e = blockIdx.x * blockDim.x + threadIdx.x;
    if (e >= N_EDGES) return;
    int d = clampi(dst[e], N_NODES);
    int pos = atomicAdd(&cursor[d], 1);
    if (pos >= 0 && pos < N_EDGES) csrsrc[pos] = clampi(src[e], N_NODES);
}

// all 4 big weights: w[K][N] fp32 -> transposed fp16 [N][K], one launch
__global__ void split_wT4(const float* __restrict__ w2, const float* __restrict__ w3,
                          const float* __restrict__ wg1, const float* __restrict__ wg2,
                          _Float16* __restrict__ out) {
    int idx = blockIdx.x * blockDim.x + threadIdx.x;
    if (idx >= 4 * H * H) return;
    int l = idx / (H * H), r = idx % (H * H);
    const float* w = (l == 0) ? w2 : (l == 1) ? w3 : (l == 2) ? wg1 : wg2;
    int n = r % H, k = r / H;
    out[(size_t)l * H * H + (size_t)n * H + k] = (_Float16)w[(size_t)k * H + n];
}

// ---- fused GCN1: aggregate x (3-dim!) then matvec w1 + bias + relu + fp16 ----
__global__ void gcn1_fused(const int* __restrict__ rowptr, const int* __restrict__ csrsrc,
                           const float* __restrict__ x, const float* __restrict__ dinv,
                           const float* __restrict__ w1, const float* __restrict__ b1,
                           _Float16* __restrict__ hi) {
    int d = blockIdx.x * 2 + (threadIdx.x / 96);
    int t = threadIdx.x % 96;
    if (d >= N_NODES) return;
    float dd = dinv[d];
    float c = dd * dd;
    float s0 = x[d*3] * c, s1 = x[d*3+1] * c, s2 = x[d*3+2] * c;
    int beg = rowptr[d], end = rowptr[d + 1];
    for (int i = beg; i < end; i++) {
        int s = csrsrc[i];
        float cc = dinv[s] * dd;
        s0 += x[s*3] * cc; s1 += x[s*3+1] * cc; s2 += x[s*3+2] * cc;
    }
    int j0 = t * 8;
    h8 o;
    #pragma unroll
    for (int k = 0; k < 8; k++) {
        int j = j0 + k;
        float v = s0 * w1[j] + s1 * w1[H + j] + s2 * w1[2*H + j] + b1[j];
        o[k] = (_Float16)fmaxf(v, 0.f);
    }
    ((h8*)(hi + (size_t)d * H))[t] = o;
}

// -- fp16 MFMA GEMM, 128x128 tile, 512 threads (8 waves), dbuf, XOR-swizzled --
// Frozen at the vmcnt(0)+s_barrier drain plateau (~130 us; r7/r8/r14/r16).
__global__ __launch_bounds__(512) void gemm_f16(const _Float16* __restrict__ a,
                                                const _Float16* __restrict__ bt,
                                                _Float16* __restrict__ C, int M,
                                                const float* __restrict__ asf,
                                                const float* __restrict__ adf,
                                                float* __restrict__ aS,
                                                float* __restrict__ aD) {
    __shared__ _Float16 sA[2][128 * 32], sB[2][128 * 32];
    int tid = threadIdx.x;
    int wave = tid >> 6, lane = tid & 63;
    int quad = lane >> 4, l16 = lane & 15;

    int id = blockIdx.x;
    int x = id & 7;
    int s = id >> 3;
    int strip = x + 8 * (s / 6);
    int colt = s % 6;
    if (strip >= (N_NODES + 127) / 128) return;
    int row0 = strip * 128, col0 = colt * 128;
    int wr = (wave >> 1) * 32, wc = (wave & 1) * 64;   // 4 row-waves x 2 col-waves

    int rr = lane >> 2;
    int kc = (((lane & 3) ^ ((lane >> 3) & 3)) << 3);   // XOR-swizzled source chunk
    const _Float16* gptr[2];
    _Float16* sd0[2];
    _Float16* sd1[2];
    #pragma unroll
    for (int k = 0; k < 2; k++) {
        int sg = wave * 2 + k;
        int isA = (sg < 8);
        int srow = isA ? sg : sg - 8;
        int r = (isA ? row0 : col0) + srow * 16 + rr;
        if (isA && r >= M) r = M - 1;
        gptr[k] = (isA ? a : bt) + (size_t)r * H + kc;
        sd0[k] = (isA ? sA[0] : sB[0]) + srow * 512;
        sd1[k] = (isA ? sA[1] : sB[1]) + srow * 512;
    }

    int fsw = (quad ^ ((l16 >> 1) & 3)) * 8;

    ffrag acc[2][4];
    #pragma unroll
    for (int i = 0; i < 2; i++)
        #pragma unroll
        for (int j = 0; j < 4; j++) { ffrag z = {0.f, 0.f, 0.f, 0.f}; acc[i][j] = z; }

    #pragma unroll
    for (int k = 0; k < 2; k++)
        gload_lds16(gptr[k], sd0[k]);

    #pragma unroll 1
    for (int kt = 0; kt < H / 32; kt++) {
        int cur = kt & 1;
        __syncthreads();
        if (kt + 1 < H / 32) {
            int koff = (kt + 1) * 32;
            #pragma unroll
            for (int k = 0; k < 2; k++)
                gload_lds16(gptr[k] + koff, (cur ? sd0[k] : sd1[k]));
        }

        const _Float16* pA = sA[cur];
        const _Float16* pB = sB[cur];
        h8 fa[2], fb[4];
        #pragma unroll
        for (int i = 0; i < 2; i++)
            fa[i] = *reinterpret_cast<const h8*>(&pA[(wr + i * 16 + l16) * 32 + fsw]);
        #pragma unroll
        for (int j = 0; j < 4; j++)
            fb[j] = *reinterpret_cast<const h8*>(&pB[(wc + j * 16 + l16) * 32 + fsw]);
        #pragma unroll
        for (int i = 0; i < 2; i++)
            #pragma unroll
            for (int j = 0; j < 4; j++)
                acc[i][j] = __builtin_amdgcn_mfma_f32_16x16x32_f16(fa[i], fb[j], acc[i][j], 0, 0, 0);
    }

    // epilogue: C/D layout col=lane&15, row=quad*4+reg (m89-verified); fp16 store
    #pragma unroll
    for (int i = 0; i < 2; i++)
        #pragma unroll
        for (int r = 0; r < 4; r++) {
            int row = row0 + wr + i * 16 + quad * 4 + r;
            if (row >= M) continue;
            #pragma unroll
            for (int j = 0; j < 4; j++)
                C[(size_t)row * H + col0 + wc + j * 16 + l16] = (_Float16)acc[i][j][r];
        }

    // fused GAT alpha: this wave covers one full head (64 cols) for 32 rows
    if (asf) {
        int head = (col0 + wc) >> 6;
        float as_c[4], ad_c[4];
        #pragma unroll
        for (int j = 0; j < 4; j++) {
            int col = col0 + wc + j * 16 + l16;
            as_c[j] = asf[col];
            ad_c[j] = adf[col];
        }
        #pragma unroll
        for (int i = 0; i < 2; i++)
            #pragma unroll
            for (int r = 0; r < 4; r++) {
                float ps = 0.f, pd = 0.f;
                #pragma unroll
                for (int j = 0; j < 4; j++) {
                    ps += acc[i][j][r] * as_c[j];
                    pd += acc[i][j][r] * ad_c[j];
                }
                ps += __shfl_xor(ps, 1);  pd += __shfl_xor(pd, 1);
                ps += __shfl_xor(ps, 2);  pd += __shfl_xor(pd, 2);
                ps += __shfl_xor(ps, 4);  pd += __shfl_xor(pd, 4);
                ps += __shfl_xor(ps, 8);  pd += __shfl_xor(pd, 8);
                int row = row0 + wr + i * 16 + quad * 4 + r;
                if (l16 == 0 && row < M) {
                    aS[row * NH + head] = ps;
                    aD[row * NH + head] = pd;
                }
            }
    }
}

// ------- fused GCN gather: 2 nodes/block, 16B h8 loads (r14-verified) --------
__global__ void gcn_gather(const int* __restrict__ rowptr, const int* __restrict__ csrsrc,
                           const _Float16* __restrict__ h, const float* __restrict__ dinv,
                           const float* __restrict__ bias, _Float16* __restrict__ hi) {
    int d = blockIdx.x * 2 + (threadIdx.x / 96);
    int t = threadIdx.x % 96;   // h8-chunk index (96 x 8 halves = 768)
    if (d >= N_NODES) return;
    float dd = dinv[d];
    float c = dd * dd;
    h8 v = ((const h8*)(h + (size_t)d * H))[t];
    float acc[8];
    #pragma unroll
    for (int k = 0; k < 8; k++) acc[k] = (float)v[k] * c;
    int beg = rowptr[d], end = rowptr[d + 1];
    for (int i = beg; i < end; i++) {
        int s = csrsrc[i];
        float cc = dinv[s] * dd;
        h8 u = ((const h8*)(h + (size_t)s * H))[t];
        #pragma unroll
        for (int k = 0; k < 8; k++) acc[k] += (float)u[k] * cc;
    }
    float4 b0 = ((const float4*)bias)[2 * t];
    float4 b1 = ((const float4*)bias)[2 * t + 1];
    h8 o;
    o[0] = (_Float16)fmaxf(acc[0] + b0.x, 0.f);
    o[1] = (_Float16)fmaxf(acc[1] + b0.y, 0.f);
    o[2] = (_Float16)fmaxf(acc[2] + b0.z, 0.f);
    o[3] = (_Float16)fmaxf(acc[3] + b0.w, 0.f);
    o[4] = (_Float16)fmaxf(acc[4] + b1.x, 0.f);
    o[5] = (_Float16)fmaxf(acc[5] + b1.y, 0.f);
    o[6] = (_Float16)fmaxf(acc[6] + b1.z, 0.f);
    o[7] = (_Float16)fmaxf(acc[7] + b1.w, 0.f);
    ((h8*)(hi + (size_t)d * H))[t] = o;
}

__device__ inline float lrelu(float v) { return (v > 0.f) ? v : 0.2f * v; }

// ---- GAT softmax stats: one thread per (node, head) computes the softmax and
// writes per-edge coefficients. Replaces the 3-pass x96-redundant loop that
// every gat_gather thread ran (r17 evidence: gat_gather ~85 us, VALU-heavy).
__global__ void gat_stats(const int* __restrict__ rowptr, const int* __restrict__ csrsrc,
                          const float* __restrict__ aS, const float* __restrict__ aD,
                          float* __restrict__ selfc, float* __restrict__ coef) {
    int idx = blockIdx.x * blockDim.x + threadIdx.x;
    if (idx >= N_NODES * NH) return;
    int d = idx / NH, hh = idx % NH;
    int beg = rowptr[d], end = rowptr[d + 1];
    float adv = aD[idx];
    float eself = lrelu(aS[idx] + adv);
    float m = eself;
    for (int i = beg; i < end; i++)
        m = fmaxf(m, lrelu(aS[csrsrc[i] * NH + hh] + adv));
    float ssum = __expf(eself - m);
    for (int i = beg; i < end; i++)
        ssum += __expf(lrelu(aS[csrsrc[i] * NH + hh] + adv) - m);
    float inv = 1.0f / ssum;
    selfc[idx] = __expf(eself - m) * inv;
    for (int i = beg; i < end; i++)
        coef[(size_t)i * NH + hh] = __expf(lrelu(aS[csrsrc[i] * NH + hh] + adv) - m) * inv;
}

// fused GAT aggregation: single pass, precomputed coefficients; fp16 out.
__global__ void gat_gather(const int* __restrict__ rowptr, const int* __restrict__ csrsrc,
                           const _Float16* __restrict__ h, const float* __restrict__ selfc,
                           const float* __restrict__ coef, const float* __restrict__ bias,
                           _Float16* __restrict__ hi, int relu) {
    int d = blockIdx.x * 2 + (threadIdx.x / 96);
    int t = threadIdx.x % 96;
    if (d >= N_NODES) return;
    int hh = t >> 3;
    int beg = rowptr[d], end = rowptr[d + 1];
    float cself = selfc[d * NH + hh];
    h8 v = ((const h8*)(h + (size_t)d * H))[t];
    float acc[8];
    #pragma unroll
    for (int k = 0; k < 8; k++) acc[k] = (float)v[k] * cself;
    for (int i = beg; i < end; i++) {
        int s = csrsrc[i];
        float c = coef[(size_t)i * NH + hh];
        h8 u = ((const h8*)(h + (size_t)s * H))[t];
        #pragma unroll
        for (int k = 0; k < 8; k++) acc[k] += (float)u[k] * c;
    }
    float4 b0 = ((const float4*)bias)[2 * t];
    float4 b1 = ((const float4*)bias)[2 * t + 1];
    acc[0] += b0.x; acc[1] += b0.y; acc[2] += b0.z; acc[3] += b0.w;
    acc[4] += b1.x; acc[5] += b1.y; acc[6] += b1.z; acc[7] += b1.w;
    if (relu) {
        #pragma unroll
        for (int k = 0; k < 8; k++) acc[k] = fmaxf(acc[k], 0.f);
    }
    h8 o;
    #pragma unroll
    for (int k = 0; k < 8; k++) o[k] = (_Float16)acc[k];
    ((h8*)(hi + (size_t)d * H))[t] = o;
}

// ---------------- pooling (batch is sorted), two-stage + fused mlp1+mlp2 ------
__device__ inline int lower_bound_i(const int* b, int n, int key) {
    int lo = 0, hi = n;
    while (lo < hi) { int mid = (lo + hi) >> 1; if (b[mid] < key) lo = mid + 1; else hi = mid; }
    return lo;
}

__global__ void pool_partial(const int* __restrict__ batch, const _Float16* __restrict__ h,
                             float* __restrict__ ppool) {
    int g = blockIdx.x / PCH, c = blockIdx.x % PCH;
    int t = threadIdx.x;   // 0..191, h4v chunks
    int lo = lower_bound_i(batch, N_NODES, g);
    int hi = lower_bound_i(batch, N_NODES, g + 1);
    int len = hi - lo;
    int chunk = (len + PCH - 1) / PCH;
    int s = lo + c * chunk;
    int e = s + chunk; if (e > hi) e = hi;
    float4 a = {0, 0, 0, 0};
    for (int n = s; n < e; n++) {
        h4v v = ((const h4v*)(h + (size_t)n * H))[t];
        a.x += (float)v[0]; a.y += (float)v[1]; a.z += (float)v[2]; a.w += (float)v[3];
    }
    ((float4*)(ppool + (size_t)blockIdx.x * H))[t] = a;
}

// reduce partials -> mean row -> z = relu(row@wc1+bc1) -> logits = z@wc2+bc2
__global__ __launch_bounds__(384) void pool_mlp(const int* __restrict__ batch,
                                                const float* __restrict__ ppool,
                                                const float* __restrict__ wc1,
                                                const float* __restrict__ bc1,
                                                const float* __restrict__ wc2,
                                                const float* __restrict__ bc2,
                                                float* __restrict__ out) {
    __shared__ float row[H];
    __shared__ float z[H2];
    int g = blockIdx.x, t = threadIdx.x;   // 384 threads
    int lo = lower_bound_i(batch, N_NODES, g);
    int hi = lower_bound_i(batch, N_NODES, g + 1);
    float inv = 1.0f / fmaxf((float)(hi - lo), 1.0f);
    for (int c0 = t; c0 < H; c0 += 384) {
        float a = 0.f;
        for (int c = 0; c < PCH; c++) a += ppool[(size_t)(g * PCH + c) * H + c0];
        row[c0] = a * inv;
    }
    __syncthreads();
    float acc = bc1[t];
    for (int k = 0; k < H; k++) acc += row[k] * wc1[(size_t)k * H2 + t];
    z[t] = fmaxf(acc, 0.f);
    __syncthreads();
    if (t < NC) {
        float l = bc2[t];
        for (int k = 0; k < H2; k++) l += z[k] * wc2[(size_t)k * NC + t];
        out[g * NC + t] = l;
    }
}

// ---------------- launch ----------------
extern "C" void kernel_launch(void* const* d_in, const int* in_sizes, int n_in,
                              void* d_out, int out_size, void* d_ws, size_t ws_size,
                              hipStream_t stream) {
    (void)d_ws; (void)ws_size;
    const float* x     = (const float*)d_in[0];
    const int*   ei    = (const int*)d_in[1];
    const int*   batch = (const int*)d_in[2];
    const float* w1  = (const float*)d_in[3];  const float* b1  = (const float*)d_in[4];
    const float* w2  = (const float*)d_in[5];  const float* b2  = (const float*)d_in[6];
    const float* w3  = (const float*)d_in[7];  const float* b3  = (const float*)d_in[8];
    const float* wg1 = (const float*)d_in[9];  const float* as1 = (const float*)d_in[10];
    const float* ad1 = (const float*)d_in[11]; const float* bg1 = (const float*)d_in[12];
    const float* wg2 = (const float*)d_in[13]; const float* as2 = (const float*)d_in[14];
    const float* ad2 = (const float*)d_in[15]; const float* bg2 = (const float*)d_in[16];
    const float* wc1 = (const float*)d_in[17]; const float* bc1 = (const float*)d_in[18];
    const float* wc2 = (const float*)d_in[19]; const float* bc2 = (const float*)d_in[20];

    const int* srcp = ei;            // edge_index[0]
    const int* dstp = ei + N_EDGES;  // edge_index[1]

    float *dinv, *aS, *aD, *selfc, *coef, *ppool, *zb;
    _Float16 *ah, *ch, *wh;
    int *degi, *bsum, *boff, *cursor, *rowptr, *csrsrc;
    hipGetSymbolAddress((void**)&ah,     HIP_SYMBOL(g_ah));
    hipGetSymbolAddress((void**)&ch,     HIP_SYMBOL(g_ch));
    hipGetSymbolAddress((void**)&wh,     HIP_SYMBOL(g_wh));
    hipGetSymbolAddress((void**)&dinv,   HIP_SYMBOL(g_dinv));
    hipGetSymbolAddress((void**)&degi,   HIP_SYMBOL(g_degi));
    hipGetSymbolAddress((void**)&bsum,   HIP_SYMBOL(g_bsum));
    hipGetSymbolAddress((void**)&boff,   HIP_SYMBOL(g_boff));
    hipGetSymbolAddress((void**)&cursor, HIP_SYMBOL(g_cursor));
    hipGetSymbolAddress((void**)&rowptr, HIP_SYMBOL(g_rowptr));
    hipGetSymbolAddress((void**)&csrsrc, HIP_SYMBOL(g_csrsrc));
    hipGetSymbolAddress((void**)&aS,     HIP_SYMBOL(g_aS));
    hipGetSymbolAddress((void**)&aD,     HIP_SYMBOL(g_aD));
    hipGetSymbolAddress((void**)&selfc,  HIP_SYMBOL(g_selfc));
    hipGetSymbolAddress((void**)&coef,   HIP_SYMBOL(g_coef));
    hipGetSymbolAddress((void**)&ppool,  HIP_SYMBOL(g_ppool));
    hipGetSymbolAddress((void**)&zb,     HIP_SYMBOL(g_zb));

    auto cdiv = [](int a, int b) { return (a + b - 1) / b; };
    int ggrid = 8 * cdiv(cdiv(N_NODES, 128), 8) * (H / 128);   // 2352
    int ngath = cdiv(N_NODES, 2);                              // 25000
    size_t HH = (size_t)H * H;

    // ---- weight transpose+cast, one launch, off the critical path ----
    split_wT4<<<cdiv(4*H*H,256),256,0,stream>>>(w2, w3, wg1, wg2, wh);

    // ---- CSR build (hierarchical scan) ----
    fill_i32<<<cdiv(N_NODES,256),256,0,stream>>>(degi, N_NODES, 0);
    count_deg<<<cdiv(N_EDGES,256),256,0,stream>>>(dstp, degi);
    scan1<<<NSB,256,0,stream>>>(degi, bsum);
    scan2<<<1,256,0,stream>>>(bsum, boff, rowptr);
    scan3<<<NSB,256,0,stream>>>(degi, boff, rowptr, cursor, dinv);
    bin_edges<<<cdiv(N_EDGES,256),256,0,stream>>>(srcp, dstp, cursor, csrsrc);

    // ---- GCN1: aggregate-first (3-dim) + matvec, single kernel ----
    gcn1_fused<<<ngath,192,0,stream>>>(rowptr, csrsrc, x, dinv, w1, b1, ah);

    // ---- GCN2 ----
    gemm_f16<<<ggrid,512,0,stream>>>(ah, wh + 0*HH, ch, N_NODES,
                                     (const float*)nullptr, (const float*)nullptr,
                                     (float*)nullptr, (float*)nullptr);
    gcn_gather<<<ngath,192,0,stream>>>(rowptr, csrsrc, ch, dinv, b2, ah);

    // ---- GCN3 ----
    gemm_f16<<<ggrid,512,0,stream>>>(ah, wh + 1*HH, ch, N_NODES,
                                     (const float*)nullptr, (const float*)nullptr,
                                     (float*)nullptr, (float*)nullptr);
    gcn_gather<<<ngath,192,0,stream>>>(rowptr, csrsrc, ch, dinv, b3, ah);

    // ---- GAT1 (alpha fused into GEMM; softmax precomputed; 1-pass gather) ----
    gemm_f16<<<ggrid,512,0,stream>>>(ah, wh + 2*HH, ch, N_NODES, as1, ad1, aS, aD);
    gat_stats<<<cdiv(N_NODES*NH,256),256,0,stream>>>(rowptr, csrsrc, aS, aD, selfc, coef);
    gat_gather<<<ngath,192,0,stream>>>(rowptr, csrsrc, ch, selfc, coef, bg1, ah, 1);

    // ---- GAT2 (no relu; fp16 out -> fp16 pooling) ----
    gemm_f16<<<ggrid,512,0,stream>>>(ah, wh + 3*HH, ch, N_NODES, as2, ad2, aS, aD);
    gat_stats<<<cdiv(N_NODES*NH,256),256,0,stream>>>(rowptr, csrsrc, aS, aD, selfc, coef);
    gat_gather<<<ngath,192,0,stream>>>(rowptr, csrsrc, ch, selfc, coef, bg2, ah, 0);

    // ---- pool (two-stage; stage-2 fused with mlp1+mlp2) ----
    pool_partial<<<NG*PCH,192,0,stream>>>(batch, ah, ppool);
    pool_mlp<<<NG,384,0,stream>>>(batch, ppool, wc1, bc1, wc2, bc2, (float*)d_out);
}

// Round 19
// 817.314 us; speedup vs baseline: 1.4589x; 1.1093x over previous
//
#include <hip/hip_runtime.h>
#include <math.h>

#define N_NODES 50000
#define N_EDGES 100000
#define H 768
#define NH 12
#define HD 64
#define NG 64
#define NC 10
#define H2 384
#define PCH 32   // pooling chunks per graph
#define NSB 196  // scan blocks = cdiv(N_NODES,256)

typedef _Float16 h8  __attribute__((ext_vector_type(8)));   // 8 fp16 (4 VGPR)
typedef _Float16 h4v __attribute__((ext_vector_type(4)));
typedef float    ffrag __attribute__((ext_vector_type(4))); // MFMA acc

// ---------------- static device scratch ----------------
__device__ _Float16 g_ah[(size_t)N_NODES * H];     // GEMM input acts fp16
__device__ _Float16 g_ch[(size_t)N_NODES * H];     // GEMM output / gather input fp16
__device__ _Float16 g_wh[4 * H * H];               // 4 weights^T fp16 [N][K]
__device__ float    g_dinv[N_NODES];
__device__ int      g_degi[N_NODES];
__device__ int      g_bsum[256];
__device__ int      g_boff[256];
__device__ int      g_cursor[N_NODES];
__device__ int      g_rowptr[N_NODES + 1];
__device__ int      g_csrsrc[N_EDGES];
__device__ float    g_aS[(size_t)N_NODES * NH];
__device__ float    g_aD[(size_t)N_NODES * NH];
__device__ float    g_selfc[(size_t)N_NODES * NH]; // GAT self-coefficient
__device__ float    g_coef[(size_t)N_EDGES * NH];  // GAT per-edge coefficient (4.8 MB)
__device__ float    g_ppool[(size_t)NG * PCH * H]; // pooling partials (6.3 MB)

__device__ inline int clampi(int v, int hi) { return (v < 0) ? 0 : (v >= hi ? hi - 1 : v); }

// async global->LDS, 16B per lane: lane i writes lds_base + i*16 (wave-uniform base)
__device__ inline void gload_lds16(const _Float16* g, _Float16* s) {
    __builtin_amdgcn_global_load_lds(
        (const __attribute__((address_space(1))) void*)g,
        (__attribute__((address_space(3))) void*)s, 16, 0, 0);
}

// ---------------- CSR build ----------------
__global__ void fill_i32(int* p, int n, int v) {
    int i = blockIdx.x * blockDim.x + threadIdx.x;
    if (i < n) p[i] = v;
}

__global__ void count_deg(const int* __restrict__ dst, int* __restrict__ degi) {
    int e = blockIdx.x * blockDim.x + threadIdx.x;
    if (e < N_EDGES) atomicAdd(&degi[clampi(dst[e], N_NODES)], 1);
}

// hierarchical scan (r13-verified)
__global__ __launch_bounds__(256) void scan1(const int* __restrict__ degi, int* __restrict__ bsum) {
    __shared__ int s[256];
    int b = blockIdx.x, t = threadIdx.x;
    int idx = b * 256 + t;
    s[t] = (idx < N_NODES) ? degi[idx] : 0;
    __syncthreads();
    for (int off = 128; off > 0; off >>= 1) {
        if (t < off) s[t] += s[t + off];
        __syncthreads();
    }
    if (t == 0) bsum[b] = s[0];
}

__global__ __launch_bounds__(256) void scan2(const int* __restrict__ bsum, int* __restrict__ boff,
                                             int* __restrict__ rowptr) {
    __shared__ int s[256];
    int t = threadIdx.x;
    int v = (t < NSB) ? bsum[t] : 0;
    s[t] = v;
    __syncthreads();
    for (int off = 1; off < 256; off <<= 1) {
        int x = (t >= off) ? s[t - off] : 0;
        __syncthreads();
        s[t] += x;
        __syncthreads();
    }
    if (t < NSB) boff[t] = s[t] - v;
    if (t == NSB - 1) rowptr[N_NODES] = s[t];
}

__global__ __launch_bounds__(256) void scan3(const int* __restrict__ degi, const int* __restrict__ boff,
                                             int* __restrict__ rowptr, int* __restrict__ cursor,
                                             float* __restrict__ dinv) {
    __shared__ int s[256];
    int b = blockIdx.x, t = threadIdx.x;
    int idx = b * 256 + t;
    int v = (idx < N_NODES) ? degi[idx] : 0;
    s[t] = v;
    __syncthreads();
    for (int off = 1; off < 256; off <<= 1) {
        int x = (t >= off) ? s[t - off] : 0;
        __syncthreads();
        s[t] += x;
        __syncthreads();
    }
    if (idx < N_NODES) {
        int excl = s[t] - v + boff[b];
        rowptr[idx] = excl;
        cursor[idx] = excl;
        dinv[idx] = rsqrtf((float)v + 1.0f);   // +1 = self-loop
    }
}

__global__ void bin_edges(const int* __restrict__ src, const int* __restrict__ dst,
                          int* __restrict__ cursor, int* __restrict__ csrsrc) {
    int e = blockIdx.x * blockDim.x + threadIdx.x;
    if (e >= N_EDGES) return;
    int d = clampi(dst[e], N_NODES);
    int pos = atomicAdd(&cursor[d], 1);
    if (pos >= 0 && pos < N_EDGES) csrsrc[pos] = clampi(src[e], N_NODES);
}

// all 4 big weights: w[K][N] fp32 -> transposed fp16 [N][K], one launch
__global__ void split_wT4(const float* __restrict__ w2, const float* __restrict__ w3,
                          const float* __restrict__ wg1, const float* __restrict__ wg2,
                          _Float16* __restrict__ out) {
    int idx = blockIdx.x * blockDim.x + threadIdx.x;
    if (idx >= 4 * H * H) return;
    int l = idx / (H * H), r = idx % (H * H);
    const float* w = (l == 0) ? w2 : (l == 1) ? w3 : (l == 2) ? wg1 : wg2;
    int n = r % H, k = r / H;
    out[(size_t)l * H * H + (size_t)n * H + k] = (_Float16)w[(size_t)k * H + n];
}

// ---- fused GCN1: aggregate x (3-dim!) then matvec w1 + bias + relu + fp16 ----
__global__ void gcn1_fused(const int* __restrict__ rowptr, const int* __restrict__ csrsrc,
                           const float* __restrict__ x, const float* __restrict__ dinv,
                           const float* __restrict__ w1, const float* __restrict__ b1,
                           _Float16* __restrict__ hi) {
    int d = blockIdx.x * 2 + (threadIdx.x / 96);
    int t = threadIdx.x % 96;
    if (d >= N_NODES) return;
    float dd = dinv[d];
    float c = dd * dd;
    float s0 = x[d*3] * c, s1 = x[d*3+1] * c, s2 = x[d*3+2] * c;
    int beg = rowptr[d], end = rowptr[d + 1];
    for (int i = beg; i < end; i++) {
        int s = csrsrc[i];
        float cc = dinv[s] * dd;
        s0 += x[s*3] * cc; s1 += x[s*3+1] * cc; s2 += x[s*3+2] * cc;
    }
    int j0 = t * 8;
    h8 o;
    #pragma unroll
    for (int k = 0; k < 8; k++) {
        int j = j0 + k;
        float v = s0 * w1[j] + s1 * w1[H + j] + s2 * w1[2*H + j] + b1[j];
        o[k] = (_Float16)fmaxf(v, 0.f);
    }
    ((h8*)(hi + (size_t)d * H))[t] = o;
}

// -- fp16 MFMA GEMM, 128x128 tile, 512 threads, BK=64 double-buffer ----------
// r18 test of the drain model: per-iter vmcnt(0)+s_barrier stall dominates
// (MfmaUtil 19%, all pipes idle). BK=64 halves barrier count 24->12. LDS is
// [2 buf][2 khalf][128x32] = 64 KB; each khalf subtile keeps the r15-verified
// layout + XOR swizzle. Occupancy 18.6->16 waves/CU (vs m132's 33% loss).
__global__ __launch_bounds__(512) void gemm_f16(const _Float16* __restrict__ a,
                                                const _Float16* __restrict__ bt,
                                                _Float16* __restrict__ C, int M,
                                                const float* __restrict__ asf,
                                                const float* __restrict__ adf,
                                                float* __restrict__ aS,
                                                float* __restrict__ aD) {
    __shared__ _Float16 sA[2][2][128 * 32], sB[2][2][128 * 32];
    int tid = threadIdx.x;
    int wave = tid >> 6, lane = tid & 63;
    int quad = lane >> 4, l16 = lane & 15;

    int id = blockIdx.x;
    int x = id & 7;
    int s = id >> 3;
    int strip = x + 8 * (s / 6);
    int colt = s % 6;
    if (strip >= (N_NODES + 127) / 128) return;
    int row0 = strip * 128, col0 = colt * 128;
    int wr = (wave >> 1) * 32, wc = (wave & 1) * 64;   // 4 row-waves x 2 col-waves

    // staging: 32 segs = {A,B} x khalf(2) x rowgroup(8); wave w stages 4w..4w+3
    int rr = lane >> 2;
    int kc = (((lane & 3) ^ ((lane >> 3) & 3)) << 3);   // XOR-swizzled source chunk
    const _Float16* gptr[4];
    int sel[4];      // 0 = A, 1 = B
    int soff[4];     // khalf*4096 + rowgroup*512
    #pragma unroll
    for (int k = 0; k < 4; k++) {
        int sg = wave * 4 + k;              // 0..31
        int isA = (sg < 16);
        int s2 = sg & 15;
        int khalf = s2 >> 3, rowgroup = s2 & 7;
        int r = (isA ? row0 : col0) + rowgroup * 16 + rr;
        if (isA && r >= M) r = M - 1;
        gptr[k] = (isA ? a : bt) + (size_t)r * H + khalf * 32 + kc;
        sel[k] = isA ? 0 : 1;
        soff[k] = khalf * 4096 + rowgroup * 512;
    }

    int fsw = (quad ^ ((l16 >> 1) & 3)) * 8;

    ffrag acc[2][4];
    #pragma unroll
    for (int i = 0; i < 2; i++)
        #pragma unroll
        for (int j = 0; j < 4; j++) { ffrag z = {0.f, 0.f, 0.f, 0.f}; acc[i][j] = z; }

    // prologue: stage k-tile 0 into buf 0
    #pragma unroll
    for (int k = 0; k < 4; k++)
        gload_lds16(gptr[k], (sel[k] ? &sB[0][0][0] : &sA[0][0][0]) + soff[k]);

    #pragma unroll 1
    for (int kt = 0; kt < H / 64; kt++) {
        int cur = kt & 1;
        __syncthreads();   // buf[cur] loads complete (compiler vmcnt drain)
        if (kt + 1 < H / 64) {
            int koff = (kt + 1) * 64;
            #pragma unroll
            for (int k = 0; k < 4; k++)
                gload_lds16(gptr[k] + koff,
                            (sel[k] ? &sB[cur ^ 1][0][0] : &sA[cur ^ 1][0][0]) + soff[k]);
        }

        #pragma unroll
        for (int kk = 0; kk < 2; kk++) {
            const _Float16* pA = sA[cur][kk];
            const _Float16* pB = sB[cur][kk];
            h8 fa[2], fb[4];
            #pragma unroll
            for (int i = 0; i < 2; i++)
                fa[i] = *reinterpret_cast<const h8*>(&pA[(wr + i * 16 + l16) * 32 + fsw]);
            #pragma unroll
            for (int j = 0; j < 4; j++)
                fb[j] = *reinterpret_cast<const h8*>(&pB[(wc + j * 16 + l16) * 32 + fsw]);
            #pragma unroll
            for (int i = 0; i < 2; i++)
                #pragma unroll
                for (int j = 0; j < 4; j++)
                    acc[i][j] = __builtin_amdgcn_mfma_f32_16x16x32_f16(fa[i], fb[j], acc[i][j], 0, 0, 0);
        }
    }

    // epilogue: C/D layout col=lane&15, row=quad*4+reg (m89-verified); fp16 store
    #pragma unroll
    for (int i = 0; i < 2; i++)
        #pragma unroll
        for (int r = 0; r < 4; r++) {
            int row = row0 + wr + i * 16 + quad * 4 + r;
            if (row >= M) continue;
            #pragma unroll
            for (int j = 0; j < 4; j++)
                C[(size_t)row * H + col0 + wc + j * 16 + l16] = (_Float16)acc[i][j][r];
        }

    // fused GAT alpha: this wave covers one full head (64 cols) for 32 rows
    if (asf) {
        int head = (col0 + wc) >> 6;
        float as_c[4], ad_c[4];
        #pragma unroll
        for (int j = 0; j < 4; j++) {
            int col = col0 + wc + j * 16 + l16;
            as_c[j] = asf[col];
            ad_c[j] = adf[col];
        }
        #pragma unroll
        for (int i = 0; i < 2; i++)
            #pragma unroll
            for (int r = 0; r < 4; r++) {
                float ps = 0.f, pd = 0.f;
                #pragma unroll
                for (int j = 0; j < 4; j++) {
                    ps += acc[i][j][r] * as_c[j];
                    pd += acc[i][j][r] * ad_c[j];
                }
                ps += __shfl_xor(ps, 1);  pd += __shfl_xor(pd, 1);
                ps += __shfl_xor(ps, 2);  pd += __shfl_xor(pd, 2);
                ps += __shfl_xor(ps, 4);  pd += __shfl_xor(pd, 4);
                ps += __shfl_xor(ps, 8);  pd += __shfl_xor(pd, 8);
                int row = row0 + wr + i * 16 + quad * 4 + r;
                if (l16 == 0 && row < M) {
                    aS[row * NH + head] = ps;
                    aD[row * NH + head] = pd;
                }
            }
    }
}

// ------- fused GCN gather: 2 nodes/block, 16B h8 loads (r14-verified) --------
__global__ void gcn_gather(const int* __restrict__ rowptr, const int* __restrict__ csrsrc,
                           const _Float16* __restrict__ h, const float* __restrict__ dinv,
                           const float* __restrict__ bias, _Float16* __restrict__ hi) {
    int d = blockIdx.x * 2 + (threadIdx.x / 96);
    int t = threadIdx.x % 96;   // h8-chunk index (96 x 8 halves = 768)
    if (d >= N_NODES) return;
    float dd = dinv[d];
    float c = dd * dd;
    h8 v = ((const h8*)(h + (size_t)d * H))[t];
    float acc[8];
    #pragma unroll
    for (int k = 0; k < 8; k++) acc[k] = (float)v[k] * c;
    int beg = rowptr[d], end = rowptr[d + 1];
    for (int i = beg; i < end; i++) {
        int s = csrsrc[i];
        float cc = dinv[s] * dd;
        h8 u = ((const h8*)(h + (size_t)s * H))[t];
        #pragma unroll
        for (int k = 0; k < 8; k++) acc[k] += (float)u[k] * cc;
    }
    float4 b0 = ((const float4*)bias)[2 * t];
    float4 b1 = ((const float4*)bias)[2 * t + 1];
    h8 o;
    o[0] = (_Float16)fmaxf(acc[0] + b0.x, 0.f);
    o[1] = (_Float16)fmaxf(acc[1] + b0.y, 0.f);
    o[2] = (_Float16)fmaxf(acc[2] + b0.z, 0.f);
    o[3] = (_Float16)fmaxf(acc[3] + b0.w, 0.f);
    o[4] = (_Float16)fmaxf(acc[4] + b1.x, 0.f);
    o[5] = (_Float16)fmaxf(acc[5] + b1.y, 0.f);
    o[6] = (_Float16)fmaxf(acc[6] + b1.z, 0.f);
    o[7] = (_Float16)fmaxf(acc[7] + b1.w, 0.f);
    ((h8*)(hi + (size_t)d * H))[t] = o;
}

__device__ inline float lrelu(float v) { return (v > 0.f) ? v : 0.2f * v; }

// ---- GAT softmax stats: one thread per (node, head) (r18-verified) ----
__global__ void gat_stats(const int* __restrict__ rowptr, const int* __restrict__ csrsrc,
                          const float* __restrict__ aS, const float* __restrict__ aD,
                          float* __restrict__ selfc, float* __restrict__ coef) {
    int idx = blockIdx.x * blockDim.x + threadIdx.x;
    if (idx >= N_NODES * NH) return;
    int d = idx / NH, hh = idx % NH;
    int beg = rowptr[d], end = rowptr[d + 1];
    float adv = aD[idx];
    float eself = lrelu(aS[idx] + adv);
    float m = eself;
    for (int i = beg; i < end; i++)
        m = fmaxf(m, lrelu(aS[csrsrc[i] * NH + hh] + adv));
    float ssum = __expf(eself - m);
    for (int i = beg; i < end; i++)
        ssum += __expf(lrelu(aS[csrsrc[i] * NH + hh] + adv) - m);
    float inv = 1.0f / ssum;
    selfc[idx] = __expf(eself - m) * inv;
    for (int i = beg; i < end; i++)
        coef[(size_t)i * NH + hh] = __expf(lrelu(aS[csrsrc[i] * NH + hh] + adv) - m) * inv;
}

// fused GAT aggregation: single pass, precomputed coefficients; fp16 out.
__global__ void gat_gather(const int* __restrict__ rowptr, const int* __restrict__ csrsrc,
                           const _Float16* __restrict__ h, const float* __restrict__ selfc,
                           const float* __restrict__ coef, const float* __restrict__ bias,
                           _Float16* __restrict__ hi, int relu) {
    int d = blockIdx.x * 2 + (threadIdx.x / 96);
    int t = threadIdx.x % 96;
    if (d >= N_NODES) return;
    int hh = t >> 3;
    int beg = rowptr[d], end = rowptr[d + 1];
    float cself = selfc[d * NH + hh];
    h8 v = ((const h8*)(h + (size_t)d * H))[t];
    float acc[8];
    #pragma unroll
    for (int k = 0; k < 8; k++) acc[k] = (float)v[k] * cself;
    for (int i = beg; i < end; i++) {
        int s = csrsrc[i];
        float c = coef[(size_t)i * NH + hh];
        h8 u = ((const h8*)(h + (size_t)s * H))[t];
        #pragma unroll
        for (int k = 0; k < 8; k++) acc[k] += (float)u[k] * c;
    }
    float4 b0 = ((const float4*)bias)[2 * t];
    float4 b1 = ((const float4*)bias)[2 * t + 1];
    acc[0] += b0.x; acc[1] += b0.y; acc[2] += b0.z; acc[3] += b0.w;
    acc[4] += b1.x; acc[5] += b1.y; acc[6] += b1.z; acc[7] += b1.w;
    if (relu) {
        #pragma unroll
        for (int k = 0; k < 8; k++) acc[k] = fmaxf(acc[k], 0.f);
    }
    h8 o;
    #pragma unroll
    for (int k = 0; k < 8; k++) o[k] = (_Float16)acc[k];
    ((h8*)(hi + (size_t)d * H))[t] = o;
}

// ---------------- pooling (batch is sorted), two-stage + fused mlp1+mlp2 ------
__device__ inline int lower_bound_i(const int* b, int n, int key) {
    int lo = 0, hi = n;
    while (lo < hi) { int mid = (lo + hi) >> 1; if (b[mid] < key) lo = mid + 1; else hi = mid; }
    return lo;
}

__global__ void pool_partial(const int* __restrict__ batch, const _Float16* __restrict__ h,
                             float* __restrict__ ppool) {
    int g = blockIdx.x / PCH, c = blockIdx.x % PCH;
    int t = threadIdx.x;   // 0..191, h4v chunks
    int lo = lower_bound_i(batch, N_NODES, g);
    int hi = lower_bound_i(batch, N_NODES, g + 1);
    int len = hi - lo;
    int chunk = (len + PCH - 1) / PCH;
    int s = lo + c * chunk;
    int e = s + chunk; if (e > hi) e = hi;
    float4 a = {0, 0, 0, 0};
    for (int n = s; n < e; n++) {
        h4v v = ((const h4v*)(h + (size_t)n * H))[t];
        a.x += (float)v[0]; a.y += (float)v[1]; a.z += (float)v[2]; a.w += (float)v[3];
    }
    ((float4*)(ppool + (size_t)blockIdx.x * H))[t] = a;
}

// reduce partials -> mean row -> z = relu(row@wc1+bc1) -> logits = z@wc2+bc2
__global__ __launch_bounds__(384) void pool_mlp(const int* __restrict__ batch,
                                                const float* __restrict__ ppool,
                                                const float* __restrict__ wc1,
                                                const float* __restrict__ bc1,
                                                const float* __restrict__ wc2,
                                                const float* __restrict__ bc2,
                                                float* __restrict__ out) {
    __shared__ float row[H];
    __shared__ float z[H2];
    int g = blockIdx.x, t = threadIdx.x;   // 384 threads
    int lo = lower_bound_i(batch, N_NODES, g);
    int hi = lower_bound_i(batch, N_NODES, g + 1);
    float inv = 1.0f / fmaxf((float)(hi - lo), 1.0f);
    for (int c0 = t; c0 < H; c0 += 384) {
        float a = 0.f;
        for (int c = 0; c < PCH; c++) a += ppool[(size_t)(g * PCH + c) * H + c0];
        row[c0] = a * inv;
    }
    __syncthreads();
    float acc = bc1[t];
    for (int k = 0; k < H; k++) acc += row[k] * wc1[(size_t)k * H2 + t];
    z[t] = fmaxf(acc, 0.f);
    __syncthreads();
    if (t < NC) {
        float l = bc2[t];
        for (int k = 0; k < H2; k++) l += z[k] * wc2[(size_t)k * NC + t];
        out[g * NC + t] = l;
    }
}

// ---------------- launch ----------------
extern "C" void kernel_launch(void* const* d_in, const int* in_sizes, int n_in,
                              void* d_out, int out_size, void* d_ws, size_t ws_size,
                              hipStream_t stream) {
    (void)d_ws; (void)ws_size;
    const float* x     = (const float*)d_in[0];
    const int*   ei    = (const int*)d_in[1];
    const int*   batch = (const int*)d_in[2];
    const float* w1  = (const float*)d_in[3];  const float* b1  = (const float*)d_in[4];
    const float* w2  = (const float*)d_in[5];  const float* b2  = (const float*)d_in[6];
    const float* w3  = (const float*)d_in[7];  const float* b3  = (const float*)d_in[8];
    const float* wg1 = (const float*)d_in[9];  const float* as1 = (const float*)d_in[10];
    const float* ad1 = (const float*)d_in[11]; const float* bg1 = (const float*)d_in[12];
    const float* wg2 = (const float*)d_in[13]; const float* as2 = (const float*)d_in[14];
    const float* ad2 = (const float*)d_in[15]; const float* bg2 = (const float*)d_in[16];
    const float* wc1 = (const float*)d_in[17]; const float* bc1 = (const float*)d_in[18];
    const float* wc2 = (const float*)d_in[19]; const float* bc2 = (const float*)d_in[20];

    const int* srcp = ei;            // edge_index[0]
    const int* dstp = ei + N_EDGES;  // edge_index[1]

    float *dinv, *aS, *aD, *selfc, *coef, *ppool;
    _Float16 *ah, *ch, *wh;
    int *degi, *bsum, *boff, *cursor, *rowptr, *csrsrc;
    hipGetSymbolAddress((void**)&ah,     HIP_SYMBOL(g_ah));
    hipGetSymbolAddress((void**)&ch,     HIP_SYMBOL(g_ch));
    hipGetSymbolAddress((void**)&wh,     HIP_SYMBOL(g_wh));
    hipGetSymbolAddress((void**)&dinv,   HIP_SYMBOL(g_dinv));
    hipGetSymbolAddress((void**)&degi,   HIP_SYMBOL(g_degi));
    hipGetSymbolAddress((void**)&bsum,   HIP_SYMBOL(g_bsum));
    hipGetSymbolAddress((void**)&boff,   HIP_SYMBOL(g_boff));
    hipGetSymbolAddress((void**)&cursor, HIP_SYMBOL(g_cursor));
    hipGetSymbolAddress((void**)&rowptr, HIP_SYMBOL(g_rowptr));
    hipGetSymbolAddress((void**)&csrsrc, HIP_SYMBOL(g_csrsrc));
    hipGetSymbolAddress((void**)&aS,     HIP_SYMBOL(g_aS));
    hipGetSymbolAddress((void**)&aD,     HIP_SYMBOL(g_aD));
    hipGetSymbolAddress((void**)&selfc,  HIP_SYMBOL(g_selfc));
    hipGetSymbolAddress((void**)&coef,   HIP_SYMBOL(g_coef));
    hipGetSymbolAddress((void**)&ppool,  HIP_SYMBOL(g_ppool));

    auto cdiv = [](int a, int b) { return (a + b - 1) / b; };
    int ggrid = 8 * cdiv(cdiv(N_NODES, 128), 8) * (H / 128);   // 2352
    int ngath = cdiv(N_NODES, 2);                              // 25000
    size_t HH = (size_t)H * H;

    // ---- weight transpose+cast, one launch, off the critical path ----
    split_wT4<<<cdiv(4*H*H,256),256,0,stream>>>(w2, w3, wg1, wg2, wh);

    // ---- CSR build (hierarchical scan) ----
    fill_i32<<<cdiv(N_NODES,256),256,0,stream>>>(degi, N_NODES, 0);
    count_deg<<<cdiv(N_EDGES,256),256,0,stream>>>(dstp, degi);
    scan1<<<NSB,256,0,stream>>>(degi, bsum);
    scan2<<<1,256,0,stream>>>(bsum, boff, rowptr);
    scan3<<<NSB,256,0,stream>>>(degi, boff, rowptr, cursor, dinv);
    bin_edges<<<cdiv(N_EDGES,256),256,0,stream>>>(srcp, dstp, cursor, csrsrc);

    // ---- GCN1: aggregate-first (3-dim) + matvec, single kernel ----
    gcn1_fused<<<ngath,192,0,stream>>>(rowptr, csrsrc, x, dinv, w1, b1, ah);

    // ---- GCN2 ----
    gemm_f16<<<ggrid,512,0,stream>>>(ah, wh + 0*HH, ch, N_NODES,
                                     (const float*)nullptr, (const float*)nullptr,
                                     (float*)nullptr, (float*)nullptr);
    gcn_gather<<<ngath,192,0,stream>>>(rowptr, csrsrc, ch, dinv, b2, ah);

    // ---- GCN3 ----
    gemm_f16<<<ggrid,512,0,stream>>>(ah, wh + 1*HH, ch, N_NODES,
                                     (const float*)nullptr, (const float*)nullptr,
                                     (float*)nullptr, (float*)nullptr);
    gcn_gather<<<ngath,192,0,stream>>>(rowptr, csrsrc, ch, dinv, b3, ah);

    // ---- GAT1 (alpha fused into GEMM; softmax precomputed; 1-pass gather) ----
    gemm_f16<<<ggrid,512,0,stream>>>(ah, wh + 2*HH, ch, N_NODES, as1, ad1, aS, aD);
    gat_stats<<<cdiv(N_NODES*NH,256),256,0,stream>>>(rowptr, csrsrc, aS, aD, selfc, coef);
    gat_gather<<<ngath,192,0,stream>>>(rowptr, csrsrc, ch, selfc, coef, bg1, ah, 1);

    // ---- GAT2 (no relu; fp16 out -> fp16 pooling) ----
    gemm_f16<<<ggrid,512,0,stream>>>(ah, wh + 3*HH, ch, N_NODES, as2, ad2, aS, aD);
    gat_stats<<<cdiv(N_NODES*NH,256),256,0,stream>>>(rowptr, csrsrc, aS, aD, selfc, coef);
    gat_gather<<<ngath,192,0,stream>>>(rowptr, csrsrc, ch, selfc, coef, bg2, ah, 0);

    // ---- pool (two-stage; stage-2 fused with mlp1+mlp2) ----
    pool_partial<<<NG*PCH,192,0,stream>>>(batch, ah, ppool);
    pool_mlp<<<NG,384,0,stream>>>(batch, ppool, wc1, bc1, wc2, bc2, (float*)d_out);
}